// Round 1
// baseline (2611.314 us; speedup 1.0000x reference)
//
#include <hip/hip_runtime.h>
#include <hip/hip_bf16.h>

#define NNODES 50000
#define NEDGES 320000
#define EMB 128
#define DIN 192
#define NB 3
#define LAM 0.01f
#define LN_EPS 1e-5f
#define PI_F 3.14159265358979323846f

// ---- workspace layout (float offsets) ----
#define WS_ESUM 0
#define WS_W    16                       // Wfull [192][768]
#define WS_G2   (WS_W + DIN*768)         // G2 [768][128]
#define WS_PHI  (WS_G2 + 768*128)        // Phi [768][128]
#define WS_M    (WS_PHI + 768*128)       // M = comb_even @ lin_w [128][128]
#define WS_BB   (WS_M + 128*128)         // bb [768]
#define WS_GB2  (WS_BB + 768)            // g_b2 [128]
#define WS_CK   (WS_GB2 + 128)           // c_k [3][128]
#define WS_EN   (WS_CK + 384)            // energies [NE]

// Wfull[n][k*256 + (0..127 r-part | 128..255 i-part)]:
//   Wr[k][n][j] = sum_f cos(2pi f n/192) r1[k][f][j] + sin(..) i1[k][f][j]
//   Wi[k][n][j] = sum_f cos(..) i1[k][f][j] - sin(..) r1[k][f][j]
__global__ __launch_bounds__(256) void k_wfull(const float* __restrict__ r1,
                                               const float* __restrict__ i1,
                                               float* __restrict__ W) {
  int idx = blockIdx.x * 256 + threadIdx.x;       // n*768 + c, 147456 total
  int n = idx / 768, c = idx - (idx / 768) * 768;
  int k = c >> 8, r = c & 255;
  bool isI = r >= 128;
  int j = r & 127;
  const float* rk = r1 + k * DIN * EMB + j;
  const float* ik = i1 + k * DIN * EMB + j;
  const float step = 2.f * PI_F / 192.f;
  float acc = 0.f;
  for (int f = 0; f < DIN; ++f) {
    int m = (f * n) % 192;
    float sn, cs;
    sincosf(step * (float)m, &sn, &cs);
    float r1v = rk[f * EMB];
    float i1v = ik[f * EMB];
    acc += isI ? (cs * i1v - sn * r1v) : (cs * r1v + sn * i1v);
  }
  W[idx] = acc;
}

// M[j][j2] = sum_t comb_w[2j][t] * lin_w[t][j2]
__global__ __launch_bounds__(256) void k_m(const float* __restrict__ comb_w,
                                           const float* __restrict__ lin_w,
                                           float* __restrict__ M) {
  int idx = blockIdx.x * 256 + threadIdx.x;       // 16384
  int j = idx >> 7, j2 = idx & 127;
  float acc = 0.f;
  for (int t = 0; t < 128; ++t)
    acc += comb_w[(2 * j) * 128 + t] * lin_w[t * 128 + j2];
  M[idx] = acc;
}

// Phi[slot][j1]: slot = k*256 + r ; f = k*128 + (r&127)
//  r<128: (1/384) sum_n cos(2pi f n/384) fre_w[n][j1]
//  r>=128: -(1/384) sum_n sin(2pi f n/384) fre_w[n][j1]
__global__ __launch_bounds__(256) void k_phi(const float* __restrict__ fre_w,
                                             float* __restrict__ Phi) {
  int idx = blockIdx.x * 256 + threadIdx.x;       // 98304
  int slot = idx >> 7, j1 = idx & 127;
  int k = slot >> 8, r = slot & 255;
  bool isI = r >= 128;
  int f = k * 128 + (r & 127);
  const float step = 2.f * PI_F / 384.f;
  float acc = 0.f;
  for (int n = 0; n < 384; ++n) {
    int m = (f * n) % 384;
    float sn, cs;
    sincosf(step * (float)m, &sn, &cs);
    acc += (isI ? -sn : cs) * fre_w[n * 128 + j1];
  }
  Phi[idx] = acc * (1.f / 384.f);
}

// G2 = Phi @ M  [768][128]
__global__ __launch_bounds__(256) void k_g2(const float* __restrict__ Phi,
                                            const float* __restrict__ M,
                                            float* __restrict__ G2) {
  int idx = blockIdx.x * 256 + threadIdx.x;       // 98304
  int slot = idx >> 7, j2 = idx & 127;
  float acc = 0.f;
  for (int j1 = 0; j1 < 128; ++j1)
    acc += Phi[slot * 128 + j1] * M[j1 * 128 + j2];
  G2[idx] = acc;
}

// bb, g_b2, c_k
__global__ __launch_bounds__(256) void k_small(const float* __restrict__ rb1,
                                               const float* __restrict__ ib1,
                                               const float* __restrict__ fre_b,
                                               const float* __restrict__ comb_b,
                                               const float* __restrict__ lin_w,
                                               const float* __restrict__ M,
                                               const float* __restrict__ G2,
                                               float* __restrict__ bb,
                                               float* __restrict__ gb2,
                                               float* __restrict__ ck) {
  int idx = blockIdx.x * 256 + threadIdx.x;       // 1280
  if (idx < 768) {
    int k = idx >> 8, r = idx & 255;
    bb[idx] = (r >= 128) ? ib1[k * 128 + (r & 127)] : rb1[k * 128 + r];
  } else if (idx < 896) {
    int j2 = idx - 768;
    float acc = 0.f;
    for (int j = 0; j < 128; ++j) acc += fre_b[j] * M[j * 128 + j2];
    for (int t = 0; t < 128; ++t) acc += comb_b[t] * lin_w[t * 128 + j2];
    gb2[j2] = acc;
  } else if (idx < 1280) {
    int q = idx - 896;
    int k = q >> 7, j2 = q & 127;
    float acc = 0.f;
    for (int j = 0; j < 128; ++j) {
      float vr = rb1[k * 128 + j];
      vr = fmaxf(vr, 0.f); vr = (vr > LAM) ? vr - LAM : 0.f;
      float vi = ib1[k * 128 + j];
      vi = fmaxf(vi, 0.f); vi = (vi > LAM) ? vi - LAM : 0.f;
      acc += vr * G2[(k * 256 + j) * 128 + j2] + vi * G2[(k * 256 + 128 + j) * 128 + j2];
    }
    ck[k * 128 + j2] = acc;
  }
}

// energy[e] = 192 * ||x_e||^2  (Parseval); esum += energy
__global__ __launch_bounds__(256) void k_energy(const float* __restrict__ hidden,
                                                const float* __restrict__ eattr,
                                                const float* __restrict__ ett,
                                                const int* __restrict__ eidx,
                                                float* __restrict__ energies,
                                                float* __restrict__ esum) {
  int e = blockIdx.x * 256 + threadIdx.x;
  int src = eidx[e];
  const float4* h4 = (const float4*)(hidden + (size_t)src * EMB);
  float ss = 0.f;
#pragma unroll
  for (int i = 0; i < 32; ++i) {
    float4 v = h4[i];
    ss += v.x * v.x + v.y * v.y + v.z * v.z + v.w * v.w;
  }
  const float4* a4 = (const float4*)(eattr + (size_t)e * 32);
#pragma unroll
  for (int i = 0; i < 8; ++i) {
    float4 v = a4[i];
    ss += v.x * v.x + v.y * v.y + v.z * v.z + v.w * v.w;
  }
  const float4* t4 = (const float4*)(ett + (size_t)e * 32);
#pragma unroll
  for (int i = 0; i < 8; ++i) {
    float4 v = t4[i];
    ss += v.x * v.x + v.y * v.y + v.z * v.z + v.w * v.w;
  }
  float en = 192.f * ss;
  energies[e] = en;
  float tot = en;
#pragma unroll
  for (int off = 32; off > 0; off >>= 1) tot += __shfl_down(tot, off, 64);
  if ((threadIdx.x & 63) == 0) atomicAdd(esum, tot);
}

// main edge kernel: 32 edges/block, fused gather -> GEMM(192x256) -> nonlin
// -> GEMM(256x128) -> atomic scatter. Inactive bands contribute const c_k.
__global__ __launch_bounds__(256, 2) void k_edges(
    const float* __restrict__ hidden, const float* __restrict__ eattr,
    const float* __restrict__ ett, const float* __restrict__ alpha,
    const int* __restrict__ eidx, const float* __restrict__ W,
    const float* __restrict__ G2, const float* __restrict__ bb,
    const float* __restrict__ gb2, const float* __restrict__ ck,
    const float* __restrict__ energies, const float* __restrict__ esum,
    float* __restrict__ accum) {
  __shared__ float Xs[32][192];                 // 24.6 KB
  __shared__ __hip_bfloat16 Os[32][256];        // 16 KB
  __shared__ __align__(16) float WcBuf[4096];   // 16 KB (W chunk / G2 chunk)
  __shared__ float maskf[3][32];
  __shared__ int tileact[3];

  const int t = threadIdx.x;
  const int e0 = blockIdx.x * 32;
  if (t < 3) tileact[t] = 0;
  __syncthreads();

  // gather x = [hidden[src] | edge_attr | edge_time_emb]
#pragma unroll
  for (int it = 0; it < 24; ++it) {
    int i = t + it * 256;                       // < 6144
    int e = i / 192, f = i - e * 192;
    int ge = e0 + e;
    float v;
    if (f < 128)       v = hidden[(size_t)eidx[ge] * 128 + f];
    else if (f < 160)  v = eattr[(size_t)ge * 32 + (f - 128)];
    else               v = ett[(size_t)ge * 32 + (f - 160)];
    Xs[e][f] = v;
  }
  if (t < 32) {
    float en = energies[e0 + t];
    float es = *esum;
#pragma unroll
    for (int k = 0; k < NB; ++k) {
      float a = alpha[k];
      float factor = (2.f * (k + 1) - 1.f) / (2.f * NB);
      float Q = a * factor * es;
      float b = es / (a * (2.f * NB));
      bool m = (en >= Q - b) && (en <= Q + b);
      maskf[k][t] = m ? 1.f : 0.f;
      if (m) atomicOr(&tileact[k], 1);
    }
  }
  __syncthreads();

  const int eA = (t >> 5) * 4;    // stage A: 4 edges
  const int c8 = (t & 31) * 8;    //          x 8 cols
  const int e2 = (t >> 4) * 2;    // stage B: 2 edges
  const int j8 = (t & 15) * 8;    //          x 8 out cols

  float z[2][8];
#pragma unroll
  for (int j = 0; j < 8; ++j) {
    float base = gb2[j8 + j];
#pragma unroll
    for (int k = 0; k < NB; ++k)
      if (!tileact[k]) base += ck[k * 128 + j8 + j];
    z[0][j] = base;
    z[1][j] = base;
  }

  for (int k = 0; k < NB; ++k) {
    if (!tileact[k]) continue;                  // block-uniform branch
    float accA[4][8];
#pragma unroll
    for (int i = 0; i < 4; ++i)
#pragma unroll
      for (int j = 0; j < 8; ++j) accA[i][j] = 0.f;

    for (int kb = 0; kb < 192; kb += 16) {
      __syncthreads();
#pragma unroll
      for (int it = 0; it < 16; ++it) {
        int i = t + it * 256;                   // < 4096
        int f = i >> 8, c = i & 255;
        WcBuf[i] = W[(kb + f) * 768 + k * 256 + c];
      }
      __syncthreads();
#pragma unroll
      for (int f = 0; f < 16; ++f) {
        float x0 = Xs[eA + 0][kb + f];
        float x1 = Xs[eA + 1][kb + f];
        float x2 = Xs[eA + 2][kb + f];
        float x3 = Xs[eA + 3][kb + f];
        float wv[8];
        *(float4*)&wv[0] = *(const float4*)&WcBuf[f * 256 + c8];
        *(float4*)&wv[4] = *(const float4*)&WcBuf[f * 256 + c8 + 4];
#pragma unroll
        for (int j = 0; j < 8; ++j) {
          accA[0][j] = fmaf(x0, wv[j], accA[0][j]);
          accA[1][j] = fmaf(x1, wv[j], accA[1][j]);
          accA[2][j] = fmaf(x2, wv[j], accA[2][j]);
          accA[3][j] = fmaf(x3, wv[j], accA[3][j]);
        }
      }
    }
    __syncthreads();
    // nonlinearity: relu then softshrink (relu>=0 so only upper branch)
#pragma unroll
    for (int i = 0; i < 4; ++i) {
      float m = maskf[k][eA + i];
#pragma unroll
      for (int j = 0; j < 8; ++j) {
        float v = fmaf(m, accA[i][j], bb[k * 256 + c8 + j]);
        v = fmaxf(v, 0.f);
        v = (v > LAM) ? v - LAM : 0.f;
        Os[eA + i][c8 + j] = __float2bfloat16(v);
      }
    }
    // stage B: z += O' @ G2_band
    for (int sb = 0; sb < 256; sb += 32) {
      __syncthreads();
#pragma unroll
      for (int it = 0; it < 16; ++it) {
        int i = t + it * 256;                   // < 4096
        int s = i >> 7, j = i & 127;
        WcBuf[i] = G2[(k * 256 + sb + s) * 128 + j];
      }
      __syncthreads();
#pragma unroll
      for (int s = 0; s < 32; ++s) {
        float o0 = __bfloat162float(Os[e2 + 0][sb + s]);
        float o1 = __bfloat162float(Os[e2 + 1][sb + s]);
        float gv[8];
        *(float4*)&gv[0] = *(const float4*)&WcBuf[s * 128 + j8];
        *(float4*)&gv[4] = *(const float4*)&WcBuf[s * 128 + j8 + 4];
#pragma unroll
        for (int j = 0; j < 8; ++j) {
          z[0][j] = fmaf(o0, gv[j], z[0][j]);
          z[1][j] = fmaf(o1, gv[j], z[1][j]);
        }
      }
    }
  }

  int d0 = eidx[NEDGES + e0 + e2];
  int d1 = eidx[NEDGES + e0 + e2 + 1];
#pragma unroll
  for (int j = 0; j < 8; ++j) atomicAdd(&accum[(size_t)d0 * 128 + j8 + j], z[0][j]);
#pragma unroll
  for (int j = 0; j < 8; ++j) atomicAdd(&accum[(size_t)d1 * 128 + j8 + j], z[1][j]);
}

// node kernel: acc + boundary@lin_w + lin_b -> LayerNorm -> relu (in-place in d_out)
__global__ __launch_bounds__(256) void k_nodes(const float* __restrict__ boundary,
                                               const float* __restrict__ lin_w,
                                               const float* __restrict__ lin_b,
                                               const float* __restrict__ ln_g,
                                               const float* __restrict__ ln_b,
                                               float* __restrict__ out) {
  __shared__ float lw[32][128];                 // lin_w chunk
  const int t = threadIdx.x;
  const int w = t >> 6, lane = t & 63;
  const int n = blockIdx.x * 4 + w;             // 50000 = 12500*4 exact
  float a0 = out[(size_t)n * 128 + lane] + lin_b[lane];
  float a1 = out[(size_t)n * 128 + 64 + lane] + lin_b[64 + lane];
  for (int cb = 0; cb < 128; cb += 32) {
    __syncthreads();
#pragma unroll
    for (int it = 0; it < 16; ++it) {
      int i = t + it * 256;                     // < 4096
      lw[i >> 7][i & 127] = lin_w[(cb + (i >> 7)) * 128 + (i & 127)];
    }
    __syncthreads();
#pragma unroll
    for (int r = 0; r < 32; ++r) {
      float bv = boundary[(size_t)n * 128 + cb + r];
      a0 = fmaf(bv, lw[r][lane], a0);
      a1 = fmaf(bv, lw[r][64 + lane], a1);
    }
  }
  float s = a0 + a1, sq = a0 * a0 + a1 * a1;
#pragma unroll
  for (int off = 32; off > 0; off >>= 1) {
    s += __shfl_xor(s, off, 64);
    sq += __shfl_xor(sq, off, 64);
  }
  float mu = s * (1.f / 128.f);
  float var = sq * (1.f / 128.f) - mu * mu;
  float rs = 1.f / sqrtf(var + LN_EPS);
  float y0 = (a0 - mu) * rs * ln_g[lane] + ln_b[lane];
  float y1 = (a1 - mu) * rs * ln_g[64 + lane] + ln_b[64 + lane];
  out[(size_t)n * 128 + lane] = fmaxf(y0, 0.f);
  out[(size_t)n * 128 + 64 + lane] = fmaxf(y1, 0.f);
}

extern "C" void kernel_launch(void* const* d_in, const int* in_sizes, int n_in,
                              void* d_out, int out_size, void* d_ws, size_t ws_size,
                              hipStream_t stream) {
  const float* hidden   = (const float*)d_in[0];
  const float* eattr    = (const float*)d_in[1];
  const float* ett      = (const float*)d_in[2];
  const float* boundary = (const float*)d_in[3];
  const float* alpha    = (const float*)d_in[4];
  const float* r1       = (const float*)d_in[5];
  const float* i1       = (const float*)d_in[6];
  const float* rb1      = (const float*)d_in[7];
  const float* ib1      = (const float*)d_in[8];
  const float* fre_w    = (const float*)d_in[9];
  const float* fre_b    = (const float*)d_in[10];
  const float* comb_b   = (const float*)d_in[12];
  const float* comb_w   = (const float*)d_in[11];
  const float* lin_w    = (const float*)d_in[13];
  const float* lin_b    = (const float*)d_in[14];
  const float* ln_g     = (const float*)d_in[15];
  const float* ln_b     = (const float*)d_in[16];
  const int*   eidx     = (const int*)d_in[17];
  float* ws  = (float*)d_ws;
  float* out = (float*)d_out;

  hipMemsetAsync(ws + WS_ESUM, 0, 16 * sizeof(float), stream);
  hipMemsetAsync(out, 0, (size_t)NNODES * EMB * sizeof(float), stream);

  k_wfull<<<576, 256, 0, stream>>>(r1, i1, ws + WS_W);
  k_m<<<64, 256, 0, stream>>>(comb_w, lin_w, ws + WS_M);
  k_phi<<<384, 256, 0, stream>>>(fre_w, ws + WS_PHI);
  k_g2<<<384, 256, 0, stream>>>(ws + WS_PHI, ws + WS_M, ws + WS_G2);
  k_small<<<5, 256, 0, stream>>>(rb1, ib1, fre_b, comb_b, lin_w, ws + WS_M,
                                 ws + WS_G2, ws + WS_BB, ws + WS_GB2, ws + WS_CK);
  k_energy<<<NEDGES / 256, 256, 0, stream>>>(hidden, eattr, ett, eidx,
                                             ws + WS_EN, ws + WS_ESUM);
  k_edges<<<NEDGES / 32, 256, 0, stream>>>(hidden, eattr, ett, alpha, eidx,
                                           ws + WS_W, ws + WS_G2, ws + WS_BB,
                                           ws + WS_GB2, ws + WS_CK, ws + WS_EN,
                                           ws + WS_ESUM, out);
  k_nodes<<<NNODES / 4, 256, 0, stream>>>(boundary, lin_w, lin_b, ln_g, ln_b, out);
}

// Round 2
// 737.295 us; speedup vs baseline: 3.5417x; 3.5417x over previous
//
#include <hip/hip_runtime.h>
#include <hip/hip_bf16.h>

#define NNODES 50000
#define NEDGES 320000
#define EMB 128
#define DIN 192
#define NB 3
#define LAM 0.01f
#define LN_EPS 1e-5f
#define PI_F 3.14159265358979323846f

typedef __attribute__((ext_vector_type(8))) short v8s;
typedef __attribute__((ext_vector_type(4))) float v4f;
typedef __attribute__((ext_vector_type(2))) float v2f;

// ---- workspace layout (float offsets) ----
#define WS_ESUM 0
#define WS_WB   16                        // Wb bf16 [3][6][16][64][8] = 147456 bf16
#define WS_G2B  (WS_WB + 73728)           // G2b bf16 [3][8][8][64][8] = 98304 bf16
#define WS_G2   (WS_G2B + 49152)          // G2 fp32 [768][128]
#define WS_PHI  (WS_G2 + 98304)           // Phi [768][128]
#define WS_M    (WS_PHI + 98304)          // M [128][128]
#define WS_BB   (WS_M + 16384)            // bb [768]
#define WS_GB2  (WS_BB + 768)             // g_b2 [128]
#define WS_CK   (WS_GB2 + 128)            // c_k [3][128]
#define WS_EN   (WS_CK + 384)             // energies [NE]

__device__ __forceinline__ unsigned pk2(float a, float b) {
  __hip_bfloat162 h2 = __float22bfloat162_rn(make_float2(a, b));
  return *reinterpret_cast<unsigned*>(&h2);
}

__device__ __forceinline__ void atomic2(float* dp, float a, float b) {
#if __has_builtin(__builtin_amdgcn_flat_atomic_fadd_v2f32)
  v2f val; val.x = a; val.y = b;
  __builtin_amdgcn_flat_atomic_fadd_v2f32((v2f*)dp, val);
#else
  atomicAdd(dp, a); atomicAdd(dp + 1, b);
#endif
}

// Wb in MFMA B-frag order: Wb[k][kc][nt][lane][j] =
//   W[f = kc*32 + (lane>>4)*8 + j][colband = nt*16 + (lane&15)]
// where W[n][k*256 + c]: c<128 -> Wr (cos*r1 + sin*i1), c>=128 -> Wi (cos*i1 - sin*r1)
__global__ __launch_bounds__(256) void k_wfull(const float* __restrict__ r1,
                                               const float* __restrict__ i1,
                                               __hip_bfloat16* __restrict__ Wb) {
  __shared__ float cs[192], sn[192];
  const int t = threadIdx.x;
  if (t < 192) sincosf((2.f * PI_F / 192.f) * (float)t, &sn[t], &cs[t]);
  __syncthreads();
  int idx = blockIdx.x * 256 + t;                  // 147456 total
  int n = idx / 768, c = idx - (idx / 768) * 768;  // n in [0,192), c in [0,768)
  int k = c >> 8, col = c & 255;
  int isI = col >> 7, j = col & 127;
  const float* ap = (isI ? i1 : r1) + (size_t)k * DIN * EMB + j;  // cos coeff
  const float* bp = (isI ? r1 : i1) + (size_t)k * DIN * EMB + j;  // sin coeff
  float sgn = isI ? -1.f : 1.f;
  float acc = 0.f;
  int m = 0;
  for (int f = 0; f < DIN; ++f) {
    acc = fmaf(cs[m], ap[(size_t)f * EMB], fmaf(sgn * sn[m], bp[(size_t)f * EMB], acc));
    m += n; if (m >= 192) m -= 192;
  }
  int kc = n >> 5, quad = (n & 31) >> 3, jj = n & 7;
  int lane = quad * 16 + (col & 15);
  Wb[((((k * 6 + kc) * 16 + (col >> 4)) * 64) + lane) * 8 + jj] = __float2bfloat16(acc);
}

// M[j][j2] = sum_t comb_w[2j][t] * lin_w[t][j2]
__global__ __launch_bounds__(256) void k_m(const float* __restrict__ comb_w,
                                           const float* __restrict__ lin_w,
                                           float* __restrict__ M) {
  int idx = blockIdx.x * 256 + threadIdx.x;        // 16384
  int j = idx >> 7, j2 = idx & 127;
  float acc = 0.f;
  for (int tt = 0; tt < 128; ++tt)
    acc = fmaf(comb_w[(2 * j) * 128 + tt], lin_w[tt * 128 + j2], acc);
  M[idx] = acc;
}

// Phi[slot][j1]: slot = k*256 + r ; f = k*128 + (r&127)
__global__ __launch_bounds__(256) void k_phi(const float* __restrict__ fre_w,
                                             float* __restrict__ Phi) {
  __shared__ float cs[384], sn[384];
  const int t = threadIdx.x;
  for (int i = t; i < 384; i += 256)
    sincosf((2.f * PI_F / 384.f) * (float)i, &sn[i], &cs[i]);
  __syncthreads();
  int idx = blockIdx.x * 256 + t;                  // 98304
  int slot = idx >> 7, j1 = idx & 127;
  int k = slot >> 8, r = slot & 255;
  int isI = r >> 7;
  int f = k * 128 + (r & 127);                     // < 384
  const float* tp = isI ? sn : cs;
  float sg = isI ? -1.f : 1.f;
  float acc = 0.f;
  int m = 0;
  for (int n = 0; n < 384; ++n) {
    acc = fmaf(sg * tp[m], fre_w[n * 128 + j1], acc);
    m += f; if (m >= 384) m -= 384;
  }
  Phi[slot * 128 + j1] = acc * (1.f / 384.f);
}

// G2 = Phi @ M (fp32) + G2b in MFMA B-frag order (bf16)
__global__ __launch_bounds__(256) void k_g2(const float* __restrict__ Phi,
                                            const float* __restrict__ M,
                                            float* __restrict__ G2,
                                            __hip_bfloat16* __restrict__ G2b) {
  int idx = blockIdx.x * 256 + threadIdx.x;        // 98304
  int slot = idx >> 7, j2 = idx & 127;
  float acc = 0.f;
  for (int j1 = 0; j1 < 128; ++j1)
    acc = fmaf(Phi[slot * 128 + j1], M[j1 * 128 + j2], acc);
  G2[idx] = acc;
  int k = slot >> 8, s = slot & 255;
  int kc = s >> 5, quad = (s & 31) >> 3, jj = s & 7;
  G2b[((((k * 8 + kc) * 8 + (j2 >> 4)) * 64) + quad * 16 + (j2 & 15)) * 8 + jj] =
      __float2bfloat16(acc);
}

// bb, g_b2, c_k
__global__ __launch_bounds__(256) void k_small(const float* __restrict__ rb1,
                                               const float* __restrict__ ib1,
                                               const float* __restrict__ fre_b,
                                               const float* __restrict__ comb_b,
                                               const float* __restrict__ lin_w,
                                               const float* __restrict__ M,
                                               const float* __restrict__ G2,
                                               float* __restrict__ bb,
                                               float* __restrict__ gb2,
                                               float* __restrict__ ck) {
  int idx = blockIdx.x * 256 + threadIdx.x;        // 1280
  if (idx < 768) {
    int k = idx >> 8, r = idx & 255;
    bb[idx] = (r >= 128) ? ib1[k * 128 + (r & 127)] : rb1[k * 128 + r];
  } else if (idx < 896) {
    int j2 = idx - 768;
    float acc = 0.f;
    for (int j = 0; j < 128; ++j) acc += fre_b[j] * M[j * 128 + j2];
    for (int tt = 0; tt < 128; ++tt) acc += comb_b[tt] * lin_w[tt * 128 + j2];
    gb2[j2] = acc;
  } else if (idx < 1280) {
    int q = idx - 896;
    int k = q >> 7, j2 = q & 127;
    float acc = 0.f;
    for (int j = 0; j < 128; ++j) {
      float vr = rb1[k * 128 + j];
      vr = fmaxf(vr, 0.f); vr = (vr > LAM) ? vr - LAM : 0.f;
      float vi = ib1[k * 128 + j];
      vi = fmaxf(vi, 0.f); vi = (vi > LAM) ? vi - LAM : 0.f;
      acc += vr * G2[(k * 256 + j) * 128 + j2] + vi * G2[(k * 256 + 128 + j) * 128 + j2];
    }
    ck[k * 128 + j2] = acc;
  }
}

// energy[e] = 192 * ||x_e||^2  (Parseval); esum += energy
__global__ __launch_bounds__(256) void k_energy(const float* __restrict__ hidden,
                                                const float* __restrict__ eattr,
                                                const float* __restrict__ ett,
                                                const int* __restrict__ eidx,
                                                float* __restrict__ energies,
                                                float* __restrict__ esum) {
  int e = blockIdx.x * 256 + threadIdx.x;
  int src = eidx[e];
  const float4* h4 = (const float4*)(hidden + (size_t)src * EMB);
  float ss = 0.f;
#pragma unroll
  for (int i = 0; i < 32; ++i) {
    float4 v = h4[i];
    ss += v.x * v.x + v.y * v.y + v.z * v.z + v.w * v.w;
  }
  const float4* a4 = (const float4*)(eattr + (size_t)e * 32);
#pragma unroll
  for (int i = 0; i < 8; ++i) {
    float4 v = a4[i];
    ss += v.x * v.x + v.y * v.y + v.z * v.z + v.w * v.w;
  }
  const float4* t4 = (const float4*)(ett + (size_t)e * 32);
#pragma unroll
  for (int i = 0; i < 8; ++i) {
    float4 v = t4[i];
    ss += v.x * v.x + v.y * v.y + v.z * v.z + v.w * v.w;
  }
  float en = 192.f * ss;
  energies[e] = en;
  float tot = en;
#pragma unroll
  for (int off = 32; off > 0; off >>= 1) tot += __shfl_down(tot, off, 64);
  if ((threadIdx.x & 63) == 0) atomicAdd(esum, tot);
}

// ---- main edge kernel: 64 edges/block, MFMA both GEMM stages ----
// stage A: X[64x192] @ Wband[192x256] (B-frags direct from global, L2-resident)
// stage B: O'[64x256] @ G2band[256x128]
#define XS_STR 200
#define OS_STR 264
__global__ __launch_bounds__(256, 2) void k_edges(
    const float* __restrict__ hidden, const float* __restrict__ eattr,
    const float* __restrict__ ett, const float* __restrict__ alpha,
    const int* __restrict__ eidx, const __hip_bfloat16* __restrict__ Wb,
    const __hip_bfloat16* __restrict__ G2b, const float* __restrict__ bb,
    const float* __restrict__ gb2, const float* __restrict__ ck,
    const float* __restrict__ energies, const float* __restrict__ esum,
    float* __restrict__ accum) {
  __shared__ __align__(16) short Xs[64 * XS_STR];   // 25600 B
  __shared__ __align__(16) short Os[64 * OS_STR];   // 33792 B
  __shared__ float maskf[3][64];
  __shared__ int srcs[64], dsts[64];
  __shared__ int tileact[3];

  const int t = threadIdx.x;
  const int e0 = blockIdx.x * 64;
  const int lane = t & 63, w = t >> 6;
  const int quad = lane >> 4, lc = lane & 15;

  if (t < 3) tileact[t] = 0;
  if (t < 64) { srcs[t] = eidx[e0 + t]; dsts[t] = eidx[NEDGES + e0 + t]; }
  __syncthreads();

  // gather x = [hidden[src] | edge_attr | edge_time_emb] -> bf16 LDS
#pragma unroll
  for (int it = 0; it < 8; ++it) {
    int i = t + it * 256;                           // < 2048
    int e = i >> 5, c4 = i & 31;
    const float4 v = *(const float4*)(hidden + (size_t)srcs[e] * 128 + c4 * 4);
    unsigned* p = (unsigned*)&Xs[e * XS_STR + c4 * 4];
    p[0] = pk2(v.x, v.y); p[1] = pk2(v.z, v.w);
  }
#pragma unroll
  for (int it = 0; it < 4; ++it) {
    int i = t + it * 256;                           // < 1024
    int e = i >> 4, q = i & 15;
    float4 v;
    if (q < 8) v = ((const float4*)(eattr + (size_t)(e0 + e) * 32))[q];
    else       v = ((const float4*)(ett + (size_t)(e0 + e) * 32))[q - 8];
    unsigned* p = (unsigned*)&Xs[e * XS_STR + 128 + q * 4];
    p[0] = pk2(v.x, v.y); p[1] = pk2(v.z, v.w);
  }
  if (t < 64) {
    float en = energies[e0 + t];
    float es = *esum;
#pragma unroll
    for (int k = 0; k < NB; ++k) {
      float a = alpha[k];
      float factor = (2.f * (k + 1) - 1.f) / (2.f * NB);
      float Q = a * factor * es;
      float b = es / (a * (2.f * NB));
      bool m = (en >= Q - b) && (en <= Q + b);
      maskf[k][t] = m ? 1.f : 0.f;
      if (m) atomicOr(&tileact[t < 64 ? 0 : 0] + k, 1);  // &tileact[k]
    }
  }
  __syncthreads();

  v4f acc2[4][2];
#pragma unroll
  for (int mt = 0; mt < 4; ++mt)
#pragma unroll
    for (int n = 0; n < 2; ++n)
#pragma unroll
      for (int r = 0; r < 4; ++r) acc2[mt][n][r] = 0.f;

  for (int k = 0; k < NB; ++k) {
    if (!tileact[k]) continue;                      // block-uniform
    v4f accA[4][4];
#pragma unroll
    for (int mt = 0; mt < 4; ++mt)
#pragma unroll
      for (int n = 0; n < 4; ++n)
#pragma unroll
        for (int r = 0; r < 4; ++r) accA[mt][n][r] = 0.f;

#pragma unroll
    for (int kc = 0; kc < 6; ++kc) {
      v8s af[4];
#pragma unroll
      for (int mt = 0; mt < 4; ++mt)
        af[mt] = *(const v8s*)&Xs[(mt * 16 + lc) * XS_STR + kc * 32 + quad * 8];
      const __hip_bfloat16* wp = Wb + ((((k * 6 + kc) * 16 + w * 4) * 64) + lane) * 8;
#pragma unroll
      for (int ntl = 0; ntl < 4; ++ntl) {
        v8s bfr = *(const v8s*)(const void*)(wp + ntl * 512);
#pragma unroll
        for (int mt = 0; mt < 4; ++mt)
          accA[mt][ntl] =
              __builtin_amdgcn_mfma_f32_16x16x32_bf16(af[mt], bfr, accA[mt][ntl], 0, 0, 0);
      }
    }
    __syncthreads();  // protect Os WAR vs previous band's stage B reads
    // nonlinearity -> Os (bf16, A-layout rows)
#pragma unroll
    for (int mt = 0; mt < 4; ++mt)
#pragma unroll
      for (int ntl = 0; ntl < 4; ++ntl) {
        int col = w * 64 + ntl * 16 + lc;
        float bbv = bb[k * 256 + col];
#pragma unroll
        for (int reg = 0; reg < 4; ++reg) {
          int row = mt * 16 + quad * 4 + reg;
          float mk = maskf[k][row];
          float v = fmaf(mk, accA[mt][ntl][reg], bbv);
          v = fmaxf(v, 0.f);
          v = (v > LAM) ? v - LAM : 0.f;
          __hip_bfloat16 h = __float2bfloat16(v);
          Os[row * OS_STR + col] = *reinterpret_cast<short*>(&h);
        }
      }
    __syncthreads();
    // stage B: acc2 += O' @ G2_band
#pragma unroll
    for (int kc = 0; kc < 8; ++kc) {
      v8s of[4];
#pragma unroll
      for (int mt = 0; mt < 4; ++mt)
        of[mt] = *(const v8s*)&Os[(mt * 16 + lc) * OS_STR + kc * 32 + quad * 8];
      const __hip_bfloat16* gp = G2b + ((((k * 8 + kc) * 8 + w * 2) * 64) + lane) * 8;
#pragma unroll
      for (int ntl = 0; ntl < 2; ++ntl) {
        v8s bfr = *(const v8s*)(const void*)(gp + ntl * 512);
#pragma unroll
        for (int mt = 0; mt < 4; ++mt)
          acc2[mt][ntl] =
              __builtin_amdgcn_mfma_f32_16x16x32_bf16(of[mt], bfr, acc2[mt][ntl], 0, 0, 0);
      }
    }
  }

  // epilogue: add base (gb2 + inactive-band consts), pair cols, v2 atomics
#pragma unroll
  for (int mt = 0; mt < 4; ++mt)
#pragma unroll
    for (int ntl = 0; ntl < 2; ++ntl) {
      int col = w * 32 + ntl * 16 + lc;
      float base = gb2[col];
#pragma unroll
      for (int k = 0; k < NB; ++k)
        if (!tileact[k]) base += ck[k * 128 + col];
#pragma unroll
      for (int reg = 0; reg < 4; ++reg) {
        float v = acc2[mt][ntl][reg] + base;
        float p = __shfl_xor(v, 1, 64);
        if (!(lane & 1)) {
          int row = mt * 16 + quad * 4 + reg;
          atomic2(accum + (size_t)dsts[row] * 128 + col, v, p);
        }
      }
    }
}

// node kernel: acc + boundary@lin_w + lin_b -> LayerNorm -> relu
__global__ __launch_bounds__(256) void k_nodes(const float* __restrict__ boundary,
                                               const float* __restrict__ lin_w,
                                               const float* __restrict__ lin_b,
                                               const float* __restrict__ ln_g,
                                               const float* __restrict__ ln_b,
                                               float* __restrict__ out) {
  __shared__ float lw[32][128];
  const int t = threadIdx.x;
  const int w = t >> 6, lane = t & 63;
  const int n = blockIdx.x * 4 + w;
  float a0 = out[(size_t)n * 128 + lane] + lin_b[lane];
  float a1 = out[(size_t)n * 128 + 64 + lane] + lin_b[64 + lane];
  for (int cb = 0; cb < 128; cb += 32) {
    __syncthreads();
#pragma unroll
    for (int it = 0; it < 16; ++it) {
      int i = t + it * 256;
      lw[i >> 7][i & 127] = lin_w[(cb + (i >> 7)) * 128 + (i & 127)];
    }
    __syncthreads();
#pragma unroll
    for (int r = 0; r < 32; ++r) {
      float bv = boundary[(size_t)n * 128 + cb + r];
      a0 = fmaf(bv, lw[r][lane], a0);
      a1 = fmaf(bv, lw[r][64 + lane], a1);
    }
  }
  float s = a0 + a1, sq = a0 * a0 + a1 * a1;
#pragma unroll
  for (int off = 32; off > 0; off >>= 1) {
    s += __shfl_xor(s, off, 64);
    sq += __shfl_xor(sq, off, 64);
  }
  float mu = s * (1.f / 128.f);
  float var = sq * (1.f / 128.f) - mu * mu;
  float rs = 1.f / sqrtf(var + LN_EPS);
  float y0 = (a0 - mu) * rs * ln_g[lane] + ln_b[lane];
  float y1 = (a1 - mu) * rs * ln_g[64 + lane] + ln_b[64 + lane];
  out[(size_t)n * 128 + lane] = fmaxf(y0, 0.f);
  out[(size_t)n * 128 + 64 + lane] = fmaxf(y1, 0.f);
}

extern "C" void kernel_launch(void* const* d_in, const int* in_sizes, int n_in,
                              void* d_out, int out_size, void* d_ws, size_t ws_size,
                              hipStream_t stream) {
  const float* hidden   = (const float*)d_in[0];
  const float* eattr    = (const float*)d_in[1];
  const float* ett      = (const float*)d_in[2];
  const float* boundary = (const float*)d_in[3];
  const float* alpha    = (const float*)d_in[4];
  const float* r1       = (const float*)d_in[5];
  const float* i1       = (const float*)d_in[6];
  const float* rb1      = (const float*)d_in[7];
  const float* ib1      = (const float*)d_in[8];
  const float* fre_w    = (const float*)d_in[9];
  const float* fre_b    = (const float*)d_in[10];
  const float* comb_w   = (const float*)d_in[11];
  const float* comb_b   = (const float*)d_in[12];
  const float* lin_w    = (const float*)d_in[13];
  const float* lin_b    = (const float*)d_in[14];
  const float* ln_g     = (const float*)d_in[15];
  const float* ln_b     = (const float*)d_in[16];
  const int*   eidx     = (const int*)d_in[17];
  float* ws  = (float*)d_ws;
  float* out = (float*)d_out;
  __hip_bfloat16* Wb  = (__hip_bfloat16*)(ws + WS_WB);
  __hip_bfloat16* G2b = (__hip_bfloat16*)(ws + WS_G2B);

  hipMemsetAsync(ws + WS_ESUM, 0, 16 * sizeof(float), stream);
  hipMemsetAsync(out, 0, (size_t)NNODES * EMB * sizeof(float), stream);

  k_wfull<<<576, 256, 0, stream>>>(r1, i1, Wb);
  k_m<<<64, 256, 0, stream>>>(comb_w, lin_w, ws + WS_M);
  k_phi<<<384, 256, 0, stream>>>(fre_w, ws + WS_PHI);
  k_g2<<<384, 256, 0, stream>>>(ws + WS_PHI, ws + WS_M, ws + WS_G2, G2b);
  k_small<<<5, 256, 0, stream>>>(rb1, ib1, fre_b, comb_b, lin_w, ws + WS_M,
                                 ws + WS_G2, ws + WS_BB, ws + WS_GB2, ws + WS_CK);
  k_energy<<<NEDGES / 256, 256, 0, stream>>>(hidden, eattr, ett, eidx,
                                             ws + WS_EN, ws + WS_ESUM);
  k_edges<<<NEDGES / 64, 256, 0, stream>>>(hidden, eattr, ett, alpha, eidx,
                                           Wb, G2b, ws + WS_BB, ws + WS_GB2,
                                           ws + WS_CK, ws + WS_EN, ws + WS_ESUM, out);
  k_nodes<<<NNODES / 4, 256, 0, stream>>>(boundary, lin_w, lin_b, ln_g, ln_b, out);
}

// Round 3
// 705.134 us; speedup vs baseline: 3.7033x; 1.0456x over previous
//
#include <hip/hip_runtime.h>
#include <hip/hip_bf16.h>

#define NNODES 50000
#define NEDGES 320000
#define EMB 128
#define DIN 192
#define NB 3
#define LAM 0.01f
#define LN_EPS 1e-5f
#define PI_F 3.14159265358979323846f

typedef __attribute__((ext_vector_type(8))) short v8s;
typedef __attribute__((ext_vector_type(4))) float v4f;
typedef __attribute__((ext_vector_type(2))) float v2f;

// ---- workspace layout (float offsets) ----
#define WS_ESUM 0
#define WS_WB   16                        // Wb bf16 [3][6][16][64][8] = 147456 bf16
#define WS_G2B  (WS_WB + 73728)           // G2b bf16 [3][8][8][64][8] = 98304 bf16
#define WS_G2   (WS_G2B + 49152)          // G2 fp32 [768][128]
#define WS_PHI  (WS_G2 + 98304)           // Phi [768][128]
#define WS_M    (WS_PHI + 98304)          // M [128][128]
#define WS_BB   (WS_M + 16384)            // bb [768]
#define WS_GB2  (WS_BB + 768)             // g_b2 [128]
#define WS_CK   (WS_GB2 + 128)            // c_k [3][128]
#define WS_EN   (WS_CK + 384)             // energies [NE]
#define WS_NORM (WS_EN + NEDGES)          // node norms [NN]

__device__ __forceinline__ unsigned pk2(float a, float b) {
  __hip_bfloat162 h2 = __float22bfloat162_rn(make_float2(a, b));
  return *reinterpret_cast<unsigned*>(&h2);
}

__device__ __forceinline__ void atomic2(float* dp, float a, float b) {
#if __has_builtin(__builtin_amdgcn_flat_atomic_fadd_v2f32)
  v2f val; val.x = a; val.y = b;
  __builtin_amdgcn_flat_atomic_fadd_v2f32((v2f*)dp, val);
#else
  atomicAdd(dp, a); atomicAdd(dp + 1, b);
#endif
}

// Wb in MFMA B-frag order: Wb[k][kc][nt][lane][j] =
//   W[f = kc*32 + (lane>>4)*8 + j][colband = nt*16 + (lane&15)]
__global__ __launch_bounds__(256) void k_wfull(const float* __restrict__ r1,
                                               const float* __restrict__ i1,
                                               __hip_bfloat16* __restrict__ Wb) {
  __shared__ float cs[192], sn[192];
  const int t = threadIdx.x;
  if (t < 192) sincosf((2.f * PI_F / 192.f) * (float)t, &sn[t], &cs[t]);
  __syncthreads();
  int idx = blockIdx.x * 256 + t;                  // 147456 total
  int n = idx / 768, c = idx - (idx / 768) * 768;
  int k = c >> 8, col = c & 255;
  int isI = col >> 7, j = col & 127;
  const float* ap = (isI ? i1 : r1) + (size_t)k * DIN * EMB + j;  // cos coeff
  const float* bp = (isI ? r1 : i1) + (size_t)k * DIN * EMB + j;  // sin coeff
  float sgn = isI ? -1.f : 1.f;
  float acc = 0.f;
  int m = 0;
  for (int f = 0; f < DIN; ++f) {
    acc = fmaf(cs[m], ap[(size_t)f * EMB], fmaf(sgn * sn[m], bp[(size_t)f * EMB], acc));
    m += n; if (m >= 192) m -= 192;
  }
  int kc = n >> 5, quad = (n & 31) >> 3, jj = n & 7;
  int lane = quad * 16 + (col & 15);
  Wb[((((k * 6 + kc) * 16 + (col >> 4)) * 64) + lane) * 8 + jj] = __float2bfloat16(acc);
}

// M[j][j2] = sum_t comb_w[2j][t] * lin_w[t][j2]
__global__ __launch_bounds__(256) void k_m(const float* __restrict__ comb_w,
                                           const float* __restrict__ lin_w,
                                           float* __restrict__ M) {
  int idx = blockIdx.x * 256 + threadIdx.x;        // 16384
  int j = idx >> 7, j2 = idx & 127;
  float acc = 0.f;
  for (int tt = 0; tt < 128; ++tt)
    acc = fmaf(comb_w[(2 * j) * 128 + tt], lin_w[tt * 128 + j2], acc);
  M[idx] = acc;
}

// Phi[slot][j1]: slot = k*256 + r ; f = k*128 + (r&127)
__global__ __launch_bounds__(256) void k_phi(const float* __restrict__ fre_w,
                                             float* __restrict__ Phi) {
  __shared__ float cs[384], sn[384];
  const int t = threadIdx.x;
  for (int i = t; i < 384; i += 256)
    sincosf((2.f * PI_F / 384.f) * (float)i, &sn[i], &cs[i]);
  __syncthreads();
  int idx = blockIdx.x * 256 + t;                  // 98304
  int slot = idx >> 7, j1 = idx & 127;
  int k = slot >> 8, r = slot & 255;
  int isI = r >> 7;
  int f = k * 128 + (r & 127);
  const float* tp = isI ? sn : cs;
  float sg = isI ? -1.f : 1.f;
  float acc = 0.f;
  int m = 0;
  for (int n = 0; n < 384; ++n) {
    acc = fmaf(sg * tp[m], fre_w[n * 128 + j1], acc);
    m += f; if (m >= 384) m -= 384;
  }
  Phi[slot * 128 + j1] = acc * (1.f / 384.f);
}

// G2 = Phi @ M (fp32) + G2b in MFMA B-frag order (bf16)
__global__ __launch_bounds__(256) void k_g2(const float* __restrict__ Phi,
                                            const float* __restrict__ M,
                                            float* __restrict__ G2,
                                            __hip_bfloat16* __restrict__ G2b) {
  int idx = blockIdx.x * 256 + threadIdx.x;        // 98304
  int slot = idx >> 7, j2 = idx & 127;
  float acc = 0.f;
  for (int j1 = 0; j1 < 128; ++j1)
    acc = fmaf(Phi[slot * 128 + j1], M[j1 * 128 + j2], acc);
  G2[idx] = acc;
  int k = slot >> 8, s = slot & 255;
  int kc = s >> 5, quad = (s & 31) >> 3, jj = s & 7;
  G2b[((((k * 8 + kc) * 8 + (j2 >> 4)) * 64) + quad * 16 + (j2 & 15)) * 8 + jj] =
      __float2bfloat16(acc);
}

// bb, g_b2, c_k
__global__ __launch_bounds__(256) void k_small(const float* __restrict__ rb1,
                                               const float* __restrict__ ib1,
                                               const float* __restrict__ fre_b,
                                               const float* __restrict__ comb_b,
                                               const float* __restrict__ lin_w,
                                               const float* __restrict__ M,
                                               const float* __restrict__ G2,
                                               float* __restrict__ bb,
                                               float* __restrict__ gb2,
                                               float* __restrict__ ck) {
  int idx = blockIdx.x * 256 + threadIdx.x;        // 1280
  if (idx < 768) {
    int k = idx >> 8, r = idx & 255;
    bb[idx] = (r >= 128) ? ib1[k * 128 + (r & 127)] : rb1[k * 128 + r];
  } else if (idx < 896) {
    int j2 = idx - 768;
    float acc = 0.f;
    for (int j = 0; j < 128; ++j) acc += fre_b[j] * M[j * 128 + j2];
    for (int tt = 0; tt < 128; ++tt) acc += comb_b[tt] * lin_w[tt * 128 + j2];
    gb2[j2] = acc;
  } else if (idx < 1280) {
    int q = idx - 896;
    int k = q >> 7, j2 = q & 127;
    float acc = 0.f;
    for (int j = 0; j < 128; ++j) {
      float vr = rb1[k * 128 + j];
      vr = fmaxf(vr, 0.f); vr = (vr > LAM) ? vr - LAM : 0.f;
      float vi = ib1[k * 128 + j];
      vi = fmaxf(vi, 0.f); vi = (vi > LAM) ? vi - LAM : 0.f;
      acc += vr * G2[(k * 256 + j) * 128 + j2] + vi * G2[(k * 256 + 128 + j) * 128 + j2];
    }
    ck[k * 128 + j2] = acc;
  }
}

// per-node ||hidden[n]||^2, coalesced (one wave per node)
__global__ __launch_bounds__(256) void k_norms(const float* __restrict__ hidden,
                                               float* __restrict__ norms) {
  const int t = threadIdx.x, w = t >> 6, lane = t & 63;
  const int n = blockIdx.x * 4 + w;                // 12500 * 4 = 50000 exact
  const float2 v = ((const float2*)(hidden + (size_t)n * 128))[lane];
  float ss = v.x * v.x + v.y * v.y;
#pragma unroll
  for (int off = 32; off > 0; off >>= 1) ss += __shfl_xor(ss, off, 64);
  if (lane == 0) norms[n] = ss;
}

// energy[e] = 192 * (norm[src] + ||ea||^2 + ||et||^2); esum += energy
__global__ __launch_bounds__(256) void k_energy(const float* __restrict__ norms,
                                                const float* __restrict__ eattr,
                                                const float* __restrict__ ett,
                                                const int* __restrict__ eidx,
                                                float* __restrict__ energies,
                                                float* __restrict__ esum) {
  int e = blockIdx.x * 256 + threadIdx.x;
  float ss = norms[eidx[e]];
  const float4* a4 = (const float4*)(eattr + (size_t)e * 32);
#pragma unroll
  for (int i = 0; i < 8; ++i) {
    float4 v = a4[i];
    ss += v.x * v.x + v.y * v.y + v.z * v.z + v.w * v.w;
  }
  const float4* t4 = (const float4*)(ett + (size_t)e * 32);
#pragma unroll
  for (int i = 0; i < 8; ++i) {
    float4 v = t4[i];
    ss += v.x * v.x + v.y * v.y + v.z * v.z + v.w * v.w;
  }
  float en = 192.f * ss;
  energies[e] = en;
  float tot = en;
#pragma unroll
  for (int off = 32; off > 0; off >>= 1) tot += __shfl_down(tot, off, 64);
  if ((threadIdx.x & 63) == 0) atomicAdd(esum, tot);
}

// ---- main edge kernel: 32 edges/block (LDS ~30 KB -> 5 blocks/CU) ----
// stage A: X[32x192] @ Wband[192x256] (B-frags direct from global, L2-resident)
// stage B: O'[32x256] @ G2band[256x128]
#define XS_STR 200
#define OS_STR 264
__global__ __launch_bounds__(256, 5) void k_edges(
    const float* __restrict__ hidden, const float* __restrict__ eattr,
    const float* __restrict__ ett, const float* __restrict__ alpha,
    const int* __restrict__ eidx, const __hip_bfloat16* __restrict__ Wb,
    const __hip_bfloat16* __restrict__ G2b, const float* __restrict__ bb,
    const float* __restrict__ gb2, const float* __restrict__ ck,
    const float* __restrict__ energies, const float* __restrict__ esum,
    float* __restrict__ accum) {
  __shared__ __align__(16) short Xs[32 * XS_STR];   // 12800 B
  __shared__ __align__(16) short Os[32 * OS_STR];   // 16896 B
  __shared__ float maskf[3][32];
  __shared__ int srcs[32], dsts[32];
  __shared__ int tileact[3];

  const int t = threadIdx.x;
  const int e0 = blockIdx.x * 32;
  const int lane = t & 63, w = t >> 6;
  const int quad = lane >> 4, lc = lane & 15;

  if (t < 3) tileact[t] = 0;
  if (t < 32) { srcs[t] = eidx[e0 + t]; dsts[t] = eidx[NEDGES + e0 + t]; }
  __syncthreads();

  // gather x = [hidden[src] | edge_attr | edge_time_emb] -> bf16 LDS
#pragma unroll
  for (int it = 0; it < 4; ++it) {
    int i = t + it * 256;                           // < 1024
    int e = i >> 5, c4 = i & 31;
    const float4 v = *(const float4*)(hidden + (size_t)srcs[e] * 128 + c4 * 4);
    unsigned* p = (unsigned*)&Xs[e * XS_STR + c4 * 4];
    p[0] = pk2(v.x, v.y); p[1] = pk2(v.z, v.w);
  }
#pragma unroll
  for (int it = 0; it < 2; ++it) {
    int i = t + it * 256;                           // < 512
    int e = i >> 4, q = i & 15;
    float4 v;
    if (q < 8) v = ((const float4*)(eattr + (size_t)(e0 + e) * 32))[q];
    else       v = ((const float4*)(ett + (size_t)(e0 + e) * 32))[q - 8];
    unsigned* p = (unsigned*)&Xs[e * XS_STR + 128 + q * 4];
    p[0] = pk2(v.x, v.y); p[1] = pk2(v.z, v.w);
  }
  if (t < 32) {
    float en = energies[e0 + t];
    float es = *esum;
#pragma unroll
    for (int k = 0; k < NB; ++k) {
      float a = alpha[k];
      float factor = (2.f * (k + 1) - 1.f) / (2.f * NB);
      float Q = a * factor * es;
      float b = es / (a * (2.f * NB));
      bool m = (en >= Q - b) && (en <= Q + b);
      maskf[k][t] = m ? 1.f : 0.f;
      if (m) atomicOr(&tileact[k], 1);
    }
  }
  __syncthreads();

  v4f acc2[2][2];
#pragma unroll
  for (int mt = 0; mt < 2; ++mt)
#pragma unroll
    for (int n = 0; n < 2; ++n)
#pragma unroll
      for (int r = 0; r < 4; ++r) acc2[mt][n][r] = 0.f;

  for (int k = 0; k < NB; ++k) {
    if (!tileact[k]) continue;                      // block-uniform
    v4f accA[2][4];
#pragma unroll
    for (int mt = 0; mt < 2; ++mt)
#pragma unroll
      for (int n = 0; n < 4; ++n)
#pragma unroll
        for (int r = 0; r < 4; ++r) accA[mt][n][r] = 0.f;

#pragma unroll
    for (int kc = 0; kc < 6; ++kc) {
      v8s af[2];
#pragma unroll
      for (int mt = 0; mt < 2; ++mt)
        af[mt] = *(const v8s*)&Xs[(mt * 16 + lc) * XS_STR + kc * 32 + quad * 8];
      const __hip_bfloat16* wp = Wb + ((((k * 6 + kc) * 16 + w * 4) * 64) + lane) * 8;
#pragma unroll
      for (int ntl = 0; ntl < 4; ++ntl) {
        v8s bfr = *(const v8s*)(const void*)(wp + ntl * 512);
#pragma unroll
        for (int mt = 0; mt < 2; ++mt)
          accA[mt][ntl] =
              __builtin_amdgcn_mfma_f32_16x16x32_bf16(af[mt], bfr, accA[mt][ntl], 0, 0, 0);
      }
    }
    __syncthreads();  // protect Os WAR vs previous band's stage B reads
    // nonlinearity -> Os (bf16, A-layout rows)
#pragma unroll
    for (int mt = 0; mt < 2; ++mt)
#pragma unroll
      for (int ntl = 0; ntl < 4; ++ntl) {
        int col = w * 64 + ntl * 16 + lc;
        float bbv = bb[k * 256 + col];
#pragma unroll
        for (int reg = 0; reg < 4; ++reg) {
          int row = mt * 16 + quad * 4 + reg;
          float mk = maskf[k][row];
          float v = fmaf(mk, accA[mt][ntl][reg], bbv);
          v = fmaxf(v, 0.f);
          v = (v > LAM) ? v - LAM : 0.f;
          __hip_bfloat16 h = __float2bfloat16(v);
          Os[row * OS_STR + col] = *reinterpret_cast<short*>(&h);
        }
      }
    __syncthreads();
    // stage B: acc2 += O' @ G2_band
#pragma unroll
    for (int kc = 0; kc < 8; ++kc) {
      v8s of[2];
#pragma unroll
      for (int mt = 0; mt < 2; ++mt)
        of[mt] = *(const v8s*)&Os[(mt * 16 + lc) * OS_STR + kc * 32 + quad * 8];
      const __hip_bfloat16* gp = G2b + ((((k * 8 + kc) * 8 + w * 2) * 64) + lane) * 8;
#pragma unroll
      for (int ntl = 0; ntl < 2; ++ntl) {
        v8s bfr = *(const v8s*)(const void*)(gp + ntl * 512);
#pragma unroll
        for (int mt = 0; mt < 2; ++mt)
          acc2[mt][ntl] =
              __builtin_amdgcn_mfma_f32_16x16x32_bf16(of[mt], bfr, acc2[mt][ntl], 0, 0, 0);
      }
    }
  }

  // epilogue: add base (gb2 + inactive-band consts), pair cols, v2 atomics
#pragma unroll
  for (int mt = 0; mt < 2; ++mt)
#pragma unroll
    for (int ntl = 0; ntl < 2; ++ntl) {
      int col = w * 32 + ntl * 16 + lc;
      float base = gb2[col];
#pragma unroll
      for (int k = 0; k < NB; ++k)
        if (!tileact[k]) base += ck[k * 128 + col];
#pragma unroll
      for (int reg = 0; reg < 4; ++reg) {
        float v = acc2[mt][ntl][reg] + base;
        float p = __shfl_xor(v, 1, 64);
        if (!(lane & 1)) {
          int row = mt * 16 + quad * 4 + reg;
          atomic2(accum + (size_t)dsts[row] * 128 + col, v, p);
        }
      }
    }
}

// node kernel: acc + boundary@lin_w + lin_b -> LayerNorm -> relu
__global__ __launch_bounds__(256) void k_nodes(const float* __restrict__ boundary,
                                               const float* __restrict__ lin_w,
                                               const float* __restrict__ lin_b,
                                               const float* __restrict__ ln_g,
                                               const float* __restrict__ ln_b,
                                               float* __restrict__ out) {
  __shared__ float lw[32][128];
  const int t = threadIdx.x;
  const int w = t >> 6, lane = t & 63;
  const int n = blockIdx.x * 4 + w;
  float a0 = out[(size_t)n * 128 + lane] + lin_b[lane];
  float a1 = out[(size_t)n * 128 + 64 + lane] + lin_b[64 + lane];
  for (int cb = 0; cb < 128; cb += 32) {
    __syncthreads();
#pragma unroll
    for (int it = 0; it < 16; ++it) {
      int i = t + it * 256;
      lw[i >> 7][i & 127] = lin_w[(cb + (i >> 7)) * 128 + (i & 127)];
    }
    __syncthreads();
#pragma unroll
    for (int r = 0; r < 32; ++r) {
      float bv = boundary[(size_t)n * 128 + cb + r];
      a0 = fmaf(bv, lw[r][lane], a0);
      a1 = fmaf(bv, lw[r][64 + lane], a1);
    }
  }
  float s = a0 + a1, sq = a0 * a0 + a1 * a1;
#pragma unroll
  for (int off = 32; off > 0; off >>= 1) {
    s += __shfl_xor(s, off, 64);
    sq += __shfl_xor(sq, off, 64);
  }
  float mu = s * (1.f / 128.f);
  float var = sq * (1.f / 128.f) - mu * mu;
  float rs = 1.f / sqrtf(var + LN_EPS);
  float y0 = (a0 - mu) * rs * ln_g[lane] + ln_b[lane];
  float y1 = (a1 - mu) * rs * ln_g[64 + lane] + ln_b[64 + lane];
  out[(size_t)n * 128 + lane] = fmaxf(y0, 0.f);
  out[(size_t)n * 128 + 64 + lane] = fmaxf(y1, 0.f);
}

extern "C" void kernel_launch(void* const* d_in, const int* in_sizes, int n_in,
                              void* d_out, int out_size, void* d_ws, size_t ws_size,
                              hipStream_t stream) {
  const float* hidden   = (const float*)d_in[0];
  const float* eattr    = (const float*)d_in[1];
  const float* ett      = (const float*)d_in[2];
  const float* boundary = (const float*)d_in[3];
  const float* alpha    = (const float*)d_in[4];
  const float* r1       = (const float*)d_in[5];
  const float* i1       = (const float*)d_in[6];
  const float* rb1      = (const float*)d_in[7];
  const float* ib1      = (const float*)d_in[8];
  const float* fre_w    = (const float*)d_in[9];
  const float* fre_b    = (const float*)d_in[10];
  const float* comb_w   = (const float*)d_in[11];
  const float* comb_b   = (const float*)d_in[12];
  const float* lin_w    = (const float*)d_in[13];
  const float* lin_b    = (const float*)d_in[14];
  const float* ln_g     = (const float*)d_in[15];
  const float* ln_b     = (const float*)d_in[16];
  const int*   eidx     = (const int*)d_in[17];
  float* ws  = (float*)d_ws;
  float* out = (float*)d_out;
  __hip_bfloat16* Wb  = (__hip_bfloat16*)(ws + WS_WB);
  __hip_bfloat16* G2b = (__hip_bfloat16*)(ws + WS_G2B);

  hipMemsetAsync(ws + WS_ESUM, 0, 16 * sizeof(float), stream);
  hipMemsetAsync(out, 0, (size_t)NNODES * EMB * sizeof(float), stream);

  k_wfull<<<576, 256, 0, stream>>>(r1, i1, Wb);
  k_m<<<64, 256, 0, stream>>>(comb_w, lin_w, ws + WS_M);
  k_phi<<<384, 256, 0, stream>>>(fre_w, ws + WS_PHI);
  k_g2<<<384, 256, 0, stream>>>(ws + WS_PHI, ws + WS_M, ws + WS_G2, G2b);
  k_small<<<5, 256, 0, stream>>>(rb1, ib1, fre_b, comb_b, lin_w, ws + WS_M,
                                 ws + WS_G2, ws + WS_BB, ws + WS_GB2, ws + WS_CK);
  k_norms<<<NNODES / 4, 256, 0, stream>>>(hidden, ws + WS_NORM);
  k_energy<<<NEDGES / 256, 256, 0, stream>>>(ws + WS_NORM, eattr, ett, eidx,
                                             ws + WS_EN, ws + WS_ESUM);
  k_edges<<<NEDGES / 32, 256, 0, stream>>>(hidden, eattr, ett, alpha, eidx,
                                           Wb, G2b, ws + WS_BB, ws + WS_GB2,
                                           ws + WS_CK, ws + WS_EN, ws + WS_ESUM, out);
  k_nodes<<<NNODES / 4, 256, 0, stream>>>(boundary, lin_w, lin_b, ln_g, ln_b, out);
}

// Round 4
// 621.391 us; speedup vs baseline: 4.2024x; 1.1348x over previous
//
#include <hip/hip_runtime.h>
#include <hip/hip_bf16.h>

#define NNODES 50000
#define NEDGES 320000
#define EMB 128
#define DIN 192
#define NB 3
#define LAM 0.01f
#define LN_EPS 1e-5f
#define PI_F 3.14159265358979323846f

#define SCAN_B 196                        // 196*256 = 50176 >= NNODES
#define SCAN_N (SCAN_B * 256)

typedef __attribute__((ext_vector_type(8))) short v8s;
typedef __attribute__((ext_vector_type(4))) float v4f;
typedef __attribute__((ext_vector_type(2))) float v2f;

// ---- workspace layout (float/int offsets on 4B units) ----
#define WS_ESUM 0
#define WS_WB   16                        // Wb bf16 [3][6][16][64][8] = 147456 bf16
#define WS_G2B  (WS_WB + 73728)           // G2b bf16 [3][8][8][64][8] = 98304 bf16
#define WS_G2   (WS_G2B + 49152)          // G2 fp32 [768][128]
#define WS_PHI  (WS_G2 + 98304)           // Phi [768][128]
#define WS_M    (WS_PHI + 98304)          // M [128][128]
#define WS_BB   (WS_M + 16384)            // bb [768]
#define WS_GB2  (WS_BB + 768)             // g_b2 [128]
#define WS_CK   (WS_GB2 + 128)            // c_k [3][128]
#define WS_EN   (WS_CK + 384)             // energies [NE]
#define WS_NORM (WS_EN + NEDGES)          // node norms [NN]
#define WS_CNT  (WS_NORM + NNODES)        // int counts/scanned [SCAN_N]
#define WS_CUR  (WS_CNT + SCAN_N)         // int cursors [SCAN_N]
#define WS_PART (WS_CUR + SCAN_N)         // int block partials [256]
#define WS_EIDS (WS_PART + 256)           // int sorted edge ids [NE]

__device__ __forceinline__ unsigned pk2(float a, float b) {
  __hip_bfloat162 h2 = __float22bfloat162_rn(make_float2(a, b));
  return *reinterpret_cast<unsigned*>(&h2);
}

__device__ __forceinline__ void atomic2(float* dp, float a, float b) {
#if __has_builtin(__builtin_amdgcn_flat_atomic_fadd_v2f32)
  v2f val; val.x = a; val.y = b;
  __builtin_amdgcn_flat_atomic_fadd_v2f32((v2f*)dp, val);
#else
  atomicAdd(dp, a); atomicAdd(dp + 1, b);
#endif
}

// Wb in MFMA B-frag order
__global__ __launch_bounds__(256) void k_wfull(const float* __restrict__ r1,
                                               const float* __restrict__ i1,
                                               __hip_bfloat16* __restrict__ Wb) {
  __shared__ float cs[192], sn[192];
  const int t = threadIdx.x;
  if (t < 192) sincosf((2.f * PI_F / 192.f) * (float)t, &sn[t], &cs[t]);
  __syncthreads();
  int idx = blockIdx.x * 256 + t;                  // 147456 total
  int n = idx / 768, c = idx - (idx / 768) * 768;
  int k = c >> 8, col = c & 255;
  int isI = col >> 7, j = col & 127;
  const float* ap = (isI ? i1 : r1) + (size_t)k * DIN * EMB + j;  // cos coeff
  const float* bp = (isI ? r1 : i1) + (size_t)k * DIN * EMB + j;  // sin coeff
  float sgn = isI ? -1.f : 1.f;
  float acc = 0.f;
  int m = 0;
  for (int f = 0; f < DIN; ++f) {
    acc = fmaf(cs[m], ap[(size_t)f * EMB], fmaf(sgn * sn[m], bp[(size_t)f * EMB], acc));
    m += n; if (m >= 192) m -= 192;
  }
  int kc = n >> 5, quad = (n & 31) >> 3, jj = n & 7;
  int lane = quad * 16 + (col & 15);
  Wb[((((k * 6 + kc) * 16 + (col >> 4)) * 64) + lane) * 8 + jj] = __float2bfloat16(acc);
}

__global__ __launch_bounds__(256) void k_m(const float* __restrict__ comb_w,
                                           const float* __restrict__ lin_w,
                                           float* __restrict__ M) {
  int idx = blockIdx.x * 256 + threadIdx.x;        // 16384
  int j = idx >> 7, j2 = idx & 127;
  float acc = 0.f;
  for (int tt = 0; tt < 128; ++tt)
    acc = fmaf(comb_w[(2 * j) * 128 + tt], lin_w[tt * 128 + j2], acc);
  M[idx] = acc;
}

__global__ __launch_bounds__(256) void k_phi(const float* __restrict__ fre_w,
                                             float* __restrict__ Phi) {
  __shared__ float cs[384], sn[384];
  const int t = threadIdx.x;
  for (int i = t; i < 384; i += 256)
    sincosf((2.f * PI_F / 384.f) * (float)i, &sn[i], &cs[i]);
  __syncthreads();
  int idx = blockIdx.x * 256 + t;                  // 98304
  int slot = idx >> 7, j1 = idx & 127;
  int k = slot >> 8, r = slot & 255;
  int isI = r >> 7;
  int f = k * 128 + (r & 127);
  const float* tp = isI ? sn : cs;
  float sg = isI ? -1.f : 1.f;
  float acc = 0.f;
  int m = 0;
  for (int n = 0; n < 384; ++n) {
    acc = fmaf(sg * tp[m], fre_w[n * 128 + j1], acc);
    m += f; if (m >= 384) m -= 384;
  }
  Phi[slot * 128 + j1] = acc * (1.f / 384.f);
}

__global__ __launch_bounds__(256) void k_g2(const float* __restrict__ Phi,
                                            const float* __restrict__ M,
                                            float* __restrict__ G2,
                                            __hip_bfloat16* __restrict__ G2b) {
  int idx = blockIdx.x * 256 + threadIdx.x;        // 98304
  int slot = idx >> 7, j2 = idx & 127;
  float acc = 0.f;
  for (int j1 = 0; j1 < 128; ++j1)
    acc = fmaf(Phi[slot * 128 + j1], M[j1 * 128 + j2], acc);
  G2[idx] = acc;
  int k = slot >> 8, s = slot & 255;
  int kc = s >> 5, quad = (s & 31) >> 3, jj = s & 7;
  G2b[((((k * 8 + kc) * 8 + (j2 >> 4)) * 64) + quad * 16 + (j2 & 15)) * 8 + jj] =
      __float2bfloat16(acc);
}

__global__ __launch_bounds__(256) void k_small(const float* __restrict__ rb1,
                                               const float* __restrict__ ib1,
                                               const float* __restrict__ fre_b,
                                               const float* __restrict__ comb_b,
                                               const float* __restrict__ lin_w,
                                               const float* __restrict__ M,
                                               const float* __restrict__ G2,
                                               float* __restrict__ bb,
                                               float* __restrict__ gb2,
                                               float* __restrict__ ck) {
  int idx = blockIdx.x * 256 + threadIdx.x;        // 1280
  if (idx < 768) {
    int k = idx >> 8, r = idx & 255;
    bb[idx] = (r >= 128) ? ib1[k * 128 + (r & 127)] : rb1[k * 128 + r];
  } else if (idx < 896) {
    int j2 = idx - 768;
    float acc = 0.f;
    for (int j = 0; j < 128; ++j) acc += fre_b[j] * M[j * 128 + j2];
    for (int tt = 0; tt < 128; ++tt) acc += comb_b[tt] * lin_w[tt * 128 + j2];
    gb2[j2] = acc;
  } else if (idx < 1280) {
    int q = idx - 896;
    int k = q >> 7, j2 = q & 127;
    float acc = 0.f;
    for (int j = 0; j < 128; ++j) {
      float vr = rb1[k * 128 + j];
      vr = fmaxf(vr, 0.f); vr = (vr > LAM) ? vr - LAM : 0.f;
      float vi = ib1[k * 128 + j];
      vi = fmaxf(vi, 0.f); vi = (vi > LAM) ? vi - LAM : 0.f;
      acc += vr * G2[(k * 256 + j) * 128 + j2] + vi * G2[(k * 256 + 128 + j) * 128 + j2];
    }
    ck[k * 128 + j2] = acc;
  }
}

// per-node ||hidden[n]||^2
__global__ __launch_bounds__(256) void k_norms(const float* __restrict__ hidden,
                                               float* __restrict__ norms) {
  const int t = threadIdx.x, w = t >> 6, lane = t & 63;
  const int n = blockIdx.x * 4 + w;
  const float2 v = ((const float2*)(hidden + (size_t)n * 128))[lane];
  float ss = v.x * v.x + v.y * v.y;
#pragma unroll
  for (int off = 32; off > 0; off >>= 1) ss += __shfl_xor(ss, off, 64);
  if (lane == 0) norms[n] = ss;
}

__global__ __launch_bounds__(256) void k_energy(const float* __restrict__ norms,
                                                const float* __restrict__ eattr,
                                                const float* __restrict__ ett,
                                                const int* __restrict__ eidx,
                                                float* __restrict__ energies,
                                                float* __restrict__ esum) {
  int e = blockIdx.x * 256 + threadIdx.x;
  float ss = norms[eidx[e]];
  const float4* a4 = (const float4*)(eattr + (size_t)e * 32);
#pragma unroll
  for (int i = 0; i < 8; ++i) {
    float4 v = a4[i];
    ss += v.x * v.x + v.y * v.y + v.z * v.z + v.w * v.w;
  }
  const float4* t4 = (const float4*)(ett + (size_t)e * 32);
#pragma unroll
  for (int i = 0; i < 8; ++i) {
    float4 v = t4[i];
    ss += v.x * v.x + v.y * v.y + v.z * v.z + v.w * v.w;
  }
  float en = 192.f * ss;
  energies[e] = en;
  float tot = en;
#pragma unroll
  for (int off = 32; off > 0; off >>= 1) tot += __shfl_down(tot, off, 64);
  if ((threadIdx.x & 63) == 0) atomicAdd(esum, tot);
}

// ---- CSR build: histogram -> 2-level exclusive scan -> fill ----
__global__ __launch_bounds__(256) void k_hist(const int* __restrict__ eidx,
                                              int* __restrict__ cnt) {
  int e = blockIdx.x * 256 + threadIdx.x;
  atomicAdd(&cnt[eidx[NEDGES + e]], 1);
}

__global__ __launch_bounds__(256) void k_scanA(const int* __restrict__ cnt,
                                               int* __restrict__ scanned,
                                               int* __restrict__ part) {
  __shared__ int sm[256];
  const int t = threadIdx.x;
  int i = blockIdx.x * 256 + t;
  int v = (i < NNODES) ? cnt[i] : 0;
  sm[t] = v;
  __syncthreads();
#pragma unroll
  for (int off = 1; off < 256; off <<= 1) {
    int x = (t >= off) ? sm[t - off] : 0;
    __syncthreads();
    sm[t] += x;
    __syncthreads();
  }
  scanned[i] = sm[t] - v;                          // exclusive
  if (t == 255) part[blockIdx.x] = sm[t];
}

__global__ __launch_bounds__(256) void k_scanB(int* __restrict__ part) {
  __shared__ int sm[256];
  const int t = threadIdx.x;
  int v = (t < SCAN_B) ? part[t] : 0;
  sm[t] = v;
  __syncthreads();
#pragma unroll
  for (int off = 1; off < 256; off <<= 1) {
    int x = (t >= off) ? sm[t - off] : 0;
    __syncthreads();
    sm[t] += x;
    __syncthreads();
  }
  if (t < SCAN_B) part[t] = sm[t] - v;             // exclusive
}

__global__ __launch_bounds__(256) void k_scanC(const int* __restrict__ scanned,
                                               const int* __restrict__ part,
                                               int* __restrict__ cur) {
  int i = blockIdx.x * 256 + threadIdx.x;
  cur[i] = scanned[i] + part[blockIdx.x];
}

__global__ __launch_bounds__(256) void k_fill(const int* __restrict__ eidx,
                                              int* __restrict__ cur,
                                              int* __restrict__ eids) {
  int e = blockIdx.x * 256 + threadIdx.x;
  int pos = atomicAdd(&cur[eidx[NEDGES + e]], 1);
  eids[pos] = e;
}

// ---- main edge kernel: 32 dst-sorted edges/block, segmented-reduce scatter ----
#define XS_STR 200
#define OS_STR 264
#define ZS_STR 130
__global__ __launch_bounds__(256, 5) void k_edges(
    const float* __restrict__ hidden, const float* __restrict__ eattr,
    const float* __restrict__ ett, const float* __restrict__ alpha,
    const int* __restrict__ eidx, const int* __restrict__ eids,
    const __hip_bfloat16* __restrict__ Wb, const __hip_bfloat16* __restrict__ G2b,
    const float* __restrict__ bb, const float* __restrict__ gb2,
    const float* __restrict__ ck, const float* __restrict__ energies,
    const float* __restrict__ esum, float* __restrict__ accum) {
  // Xs (12800 B) + Os (16896 B) live through the band loop; Zs (16640 B)
  // reuses the same region after the final band (both dead by then).
  __shared__ __align__(16) char smem[32 * XS_STR * 2 + 32 * OS_STR * 2];
  short* Xs = (short*)smem;
  short* Os = (short*)(smem + 32 * XS_STR * 2);
  float* Zs = (float*)smem;
  __shared__ float maskf[3][32];
  __shared__ int eid_s[32], srcs[32], dsts[32];
  __shared__ int tileact[3];

  const int t = threadIdx.x;
  const int e0 = blockIdx.x * 32;
  const int lane = t & 63, w = t >> 6;
  const int quad = lane >> 4, lc = lane & 15;

  if (t < 3) tileact[t] = 0;
  if (t < 32) {
    int eid = eids[e0 + t];
    eid_s[t] = eid;
    srcs[t] = eidx[eid];
    dsts[t] = eidx[NEDGES + eid];                  // non-decreasing across t
    float en = energies[eid];
    float es = *esum;
#pragma unroll
    for (int k = 0; k < NB; ++k) {
      float a = alpha[k];
      float factor = (2.f * (k + 1) - 1.f) / (2.f * NB);
      float Q = a * factor * es;
      float b = es / (a * (2.f * NB));
      bool m = (en >= Q - b) && (en <= Q + b);
      maskf[k][t] = m ? 1.f : 0.f;
      if (m) atomicOr(&tileact[k], 1);
    }
  }
  __syncthreads();

  // gather x = [hidden[src] | edge_attr | edge_time_emb] -> bf16 LDS
#pragma unroll
  for (int it = 0; it < 4; ++it) {
    int i = t + it * 256;                           // < 1024
    int e = i >> 5, c4 = i & 31;
    const float4 v = *(const float4*)(hidden + (size_t)srcs[e] * 128 + c4 * 4);
    unsigned* p = (unsigned*)&Xs[e * XS_STR + c4 * 4];
    p[0] = pk2(v.x, v.y); p[1] = pk2(v.z, v.w);
  }
#pragma unroll
  for (int it = 0; it < 2; ++it) {
    int i = t + it * 256;                           // < 512
    int e = i >> 4, q = i & 15;
    float4 v;
    if (q < 8) v = ((const float4*)(eattr + (size_t)eid_s[e] * 32))[q];
    else       v = ((const float4*)(ett + (size_t)eid_s[e] * 32))[q - 8];
    unsigned* p = (unsigned*)&Xs[e * XS_STR + 128 + q * 4];
    p[0] = pk2(v.x, v.y); p[1] = pk2(v.z, v.w);
  }
  __syncthreads();

  v4f acc2[2][2];
#pragma unroll
  for (int mt = 0; mt < 2; ++mt)
#pragma unroll
    for (int n = 0; n < 2; ++n)
#pragma unroll
      for (int r = 0; r < 4; ++r) acc2[mt][n][r] = 0.f;

  for (int k = 0; k < NB; ++k) {
    if (!tileact[k]) continue;                      // block-uniform
    v4f accA[2][4];
#pragma unroll
    for (int mt = 0; mt < 2; ++mt)
#pragma unroll
      for (int n = 0; n < 4; ++n)
#pragma unroll
        for (int r = 0; r < 4; ++r) accA[mt][n][r] = 0.f;

#pragma unroll
    for (int kc = 0; kc < 6; ++kc) {
      v8s af[2];
#pragma unroll
      for (int mt = 0; mt < 2; ++mt)
        af[mt] = *(const v8s*)&Xs[(mt * 16 + lc) * XS_STR + kc * 32 + quad * 8];
      const __hip_bfloat16* wp = Wb + ((((k * 6 + kc) * 16 + w * 4) * 64) + lane) * 8;
#pragma unroll
      for (int ntl = 0; ntl < 4; ++ntl) {
        v8s bfr = *(const v8s*)(const void*)(wp + ntl * 512);
#pragma unroll
        for (int mt = 0; mt < 2; ++mt)
          accA[mt][ntl] =
              __builtin_amdgcn_mfma_f32_16x16x32_bf16(af[mt], bfr, accA[mt][ntl], 0, 0, 0);
      }
    }
    __syncthreads();  // protect Os WAR vs previous band's stage B reads
#pragma unroll
    for (int mt = 0; mt < 2; ++mt)
#pragma unroll
      for (int ntl = 0; ntl < 4; ++ntl) {
        int col = w * 64 + ntl * 16 + lc;
        float bbv = bb[k * 256 + col];
#pragma unroll
        for (int reg = 0; reg < 4; ++reg) {
          int row = mt * 16 + quad * 4 + reg;
          float mk = maskf[k][row];
          float v = fmaf(mk, accA[mt][ntl][reg], bbv);
          v = fmaxf(v, 0.f);
          v = (v > LAM) ? v - LAM : 0.f;
          __hip_bfloat16 h = __float2bfloat16(v);
          Os[row * OS_STR + col] = *reinterpret_cast<short*>(&h);
        }
      }
    __syncthreads();
#pragma unroll
    for (int kc = 0; kc < 8; ++kc) {
      v8s of[2];
#pragma unroll
      for (int mt = 0; mt < 2; ++mt)
        of[mt] = *(const v8s*)&Os[(mt * 16 + lc) * OS_STR + kc * 32 + quad * 8];
      const __hip_bfloat16* gp = G2b + ((((k * 8 + kc) * 8 + w * 2) * 64) + lane) * 8;
#pragma unroll
      for (int ntl = 0; ntl < 2; ++ntl) {
        v8s bfr = *(const v8s*)(const void*)(gp + ntl * 512);
#pragma unroll
        for (int mt = 0; mt < 2; ++mt)
          acc2[mt][ntl] =
              __builtin_amdgcn_mfma_f32_16x16x32_bf16(of[mt], bfr, acc2[mt][ntl], 0, 0, 0);
      }
    }
  }

  // ---- epilogue: z -> Zs (LDS), then per-column segmented reduce + atomics ----
  __syncthreads();                                  // Xs/Os dead; reuse as Zs
#pragma unroll
  for (int mt = 0; mt < 2; ++mt)
#pragma unroll
    for (int ntl = 0; ntl < 2; ++ntl) {
      int col = w * 32 + ntl * 16 + lc;
      float base = gb2[col];
#pragma unroll
      for (int k = 0; k < NB; ++k)
        if (!tileact[k]) base += ck[k * 128 + col];
#pragma unroll
      for (int reg = 0; reg < 4; ++reg) {
        int row = mt * 16 + quad * 4 + reg;
        Zs[row * ZS_STR + col] = acc2[mt][ntl][reg] + base;
      }
    }
  __syncthreads();
  if (t < 64) {
    int c = 2 * t;
    float s0 = 0.f, s1 = 0.f;
#pragma unroll
    for (int r = 0; r < 32; ++r) {
      s0 += Zs[r * ZS_STR + c];
      s1 += Zs[r * ZS_STR + c + 1];
      int d = dsts[r];
      if (r == 31 || dsts[r + 1] != d) {
        atomic2(accum + (size_t)d * 128 + c, s0, s1);
        s0 = 0.f; s1 = 0.f;
      }
    }
  }
}

// node kernel: acc + boundary@lin_w + lin_b -> LayerNorm -> relu
__global__ __launch_bounds__(256) void k_nodes(const float* __restrict__ boundary,
                                               const float* __restrict__ lin_w,
                                               const float* __restrict__ lin_b,
                                               const float* __restrict__ ln_g,
                                               const float* __restrict__ ln_b,
                                               float* __restrict__ out) {
  __shared__ float lw[32][128];
  const int t = threadIdx.x;
  const int w = t >> 6, lane = t & 63;
  const int n = blockIdx.x * 4 + w;
  float a0 = out[(size_t)n * 128 + lane] + lin_b[lane];
  float a1 = out[(size_t)n * 128 + 64 + lane] + lin_b[64 + lane];
  for (int cb = 0; cb < 128; cb += 32) {
    __syncthreads();
#pragma unroll
    for (int it = 0; it < 16; ++it) {
      int i = t + it * 256;
      lw[i >> 7][i & 127] = lin_w[(cb + (i >> 7)) * 128 + (i & 127)];
    }
    __syncthreads();
#pragma unroll
    for (int r = 0; r < 32; ++r) {
      float bv = boundary[(size_t)n * 128 + cb + r];
      a0 = fmaf(bv, lw[r][lane], a0);
      a1 = fmaf(bv, lw[r][64 + lane], a1);
    }
  }
  float s = a0 + a1, sq = a0 * a0 + a1 * a1;
#pragma unroll
  for (int off = 32; off > 0; off >>= 1) {
    s += __shfl_xor(s, off, 64);
    sq += __shfl_xor(sq, off, 64);
  }
  float mu = s * (1.f / 128.f);
  float var = sq * (1.f / 128.f) - mu * mu;
  float rs = 1.f / sqrtf(var + LN_EPS);
  float y0 = (a0 - mu) * rs * ln_g[lane] + ln_b[lane];
  float y1 = (a1 - mu) * rs * ln_g[64 + lane] + ln_b[64 + lane];
  out[(size_t)n * 128 + lane] = fmaxf(y0, 0.f);
  out[(size_t)n * 128 + 64 + lane] = fmaxf(y1, 0.f);
}

extern "C" void kernel_launch(void* const* d_in, const int* in_sizes, int n_in,
                              void* d_out, int out_size, void* d_ws, size_t ws_size,
                              hipStream_t stream) {
  const float* hidden   = (const float*)d_in[0];
  const float* eattr    = (const float*)d_in[1];
  const float* ett      = (const float*)d_in[2];
  const float* boundary = (const float*)d_in[3];
  const float* alpha    = (const float*)d_in[4];
  const float* r1       = (const float*)d_in[5];
  const float* i1       = (const float*)d_in[6];
  const float* rb1      = (const float*)d_in[7];
  const float* ib1      = (const float*)d_in[8];
  const float* fre_w    = (const float*)d_in[9];
  const float* fre_b    = (const float*)d_in[10];
  const float* comb_w   = (const float*)d_in[11];
  const float* comb_b   = (const float*)d_in[12];
  const float* lin_w    = (const float*)d_in[13];
  const float* lin_b    = (const float*)d_in[14];
  const float* ln_g     = (const float*)d_in[15];
  const float* ln_b     = (const float*)d_in[16];
  const int*   eidx     = (const int*)d_in[17];
  float* ws  = (float*)d_ws;
  float* out = (float*)d_out;
  __hip_bfloat16* Wb  = (__hip_bfloat16*)(ws + WS_WB);
  __hip_bfloat16* G2b = (__hip_bfloat16*)(ws + WS_G2B);
  int* cnt  = (int*)(ws + WS_CNT);
  int* cur  = (int*)(ws + WS_CUR);
  int* part = (int*)(ws + WS_PART);
  int* eids = (int*)(ws + WS_EIDS);

  hipMemsetAsync(ws + WS_ESUM, 0, 16 * sizeof(float), stream);
  hipMemsetAsync(cnt, 0, SCAN_N * sizeof(int), stream);
  hipMemsetAsync(out, 0, (size_t)NNODES * EMB * sizeof(float), stream);

  k_wfull<<<576, 256, 0, stream>>>(r1, i1, Wb);
  k_m<<<64, 256, 0, stream>>>(comb_w, lin_w, ws + WS_M);
  k_phi<<<384, 256, 0, stream>>>(fre_w, ws + WS_PHI);
  k_g2<<<384, 256, 0, stream>>>(ws + WS_PHI, ws + WS_M, ws + WS_G2, G2b);
  k_small<<<5, 256, 0, stream>>>(rb1, ib1, fre_b, comb_b, lin_w, ws + WS_M,
                                 ws + WS_G2, ws + WS_BB, ws + WS_GB2, ws + WS_CK);
  k_norms<<<NNODES / 4, 256, 0, stream>>>(hidden, ws + WS_NORM);
  k_energy<<<NEDGES / 256, 256, 0, stream>>>(ws + WS_NORM, eattr, ett, eidx,
                                             ws + WS_EN, ws + WS_ESUM);
  k_hist<<<NEDGES / 256, 256, 0, stream>>>(eidx, cnt);
  k_scanA<<<SCAN_B, 256, 0, stream>>>(cnt, cnt, part);
  k_scanB<<<1, 256, 0, stream>>>(part);
  k_scanC<<<SCAN_B, 256, 0, stream>>>(cnt, part, cur);
  k_fill<<<NEDGES / 256, 256, 0, stream>>>(eidx, cur, eids);
  k_edges<<<NEDGES / 32, 256, 0, stream>>>(hidden, eattr, ett, alpha, eidx, eids,
                                           Wb, G2b, ws + WS_BB, ws + WS_GB2,
                                           ws + WS_CK, ws + WS_EN, ws + WS_ESUM, out);
  k_nodes<<<NNODES / 4, 256, 0, stream>>>(boundary, lin_w, lin_b, ln_g, ln_b, out);
}

// Round 5
// 553.254 us; speedup vs baseline: 4.7199x; 1.1232x over previous
//
#include <hip/hip_runtime.h>
#include <hip/hip_bf16.h>

#define NNODES 50000
#define NEDGES 320000
#define EMB 128
#define DIN 192
#define NB 3
#define LAM 0.01f
#define LN_EPS 1e-5f
#define PI_F 3.14159265358979323846f

#define SCAN_B 196                        // 196*256 = 50176 >= NNODES
#define SCAN_N (SCAN_B * 256)

typedef __attribute__((ext_vector_type(8))) short v8s;
typedef __attribute__((ext_vector_type(4))) float v4f;
typedef __attribute__((ext_vector_type(2))) float v2f;

// ---- workspace layout (4B-unit offsets) ----
#define WS_ESUM 0
#define WS_WB   16                        // Wb bf16 [3][6][16][64][8]
#define WS_G2B  (WS_WB + 73728)           // G2b bf16 [3][8][8][64][8]
#define WS_G2   (WS_G2B + 49152)          // G2 fp32 [768][128]
#define WS_PHI  (WS_G2 + 98304)           // Phi [768][128]
#define WS_M    (WS_PHI + 98304)          // M [128][128]
#define WS_BB   (WS_M + 16384)            // bb [768]
#define WS_GB2  (WS_BB + 768)             // g_b2 [128]
#define WS_CK   (WS_GB2 + 128)            // c_k [3][128]
#define WS_EN   (WS_CK + 384)             // energies [NE]
#define WS_NORM (WS_EN + NEDGES)          // node norms [NN]
#define WS_CNT  (WS_NORM + NNODES)        // int counts/scanned [SCAN_N]
#define WS_CUR  (WS_CNT + SCAN_N)         // int cursors [SCAN_N]
#define WS_PART (WS_CUR + SCAN_N)         // int block partials [256]
#define WS_EIDS (WS_PART + 256)           // int sorted edge ids [NE]

__device__ __forceinline__ unsigned pk2(float a, float b) {
  __hip_bfloat162 h2 = __float22bfloat162_rn(make_float2(a, b));
  return *reinterpret_cast<unsigned*>(&h2);
}

__device__ __forceinline__ void atomic2(float* dp, float a, float b) {
#if __has_builtin(__builtin_amdgcn_flat_atomic_fadd_v2f32)
  v2f val; val.x = a; val.y = b;
  __builtin_amdgcn_flat_atomic_fadd_v2f32((v2f*)dp, val);
#else
  atomicAdd(dp, a); atomicAdd(dp + 1, b);
#endif
}

// ---- P1: wfull(576) | m(64) | phi(384) | norms(12500) ----
__global__ __launch_bounds__(256) void k_prep1(
    const float* __restrict__ r1, const float* __restrict__ i1,
    __hip_bfloat16* __restrict__ Wb, const float* __restrict__ comb_w,
    const float* __restrict__ lin_w, float* __restrict__ M,
    const float* __restrict__ fre_w, float* __restrict__ Phi,
    const float* __restrict__ hidden, float* __restrict__ norms) {
  __shared__ float cs[384], sn[384];
  const int t = threadIdx.x;
  const int b = blockIdx.x;
  if (b < 576) {
    // Wb in MFMA B-frag order
    if (t < 192) sincosf((2.f * PI_F / 192.f) * (float)t, &sn[t], &cs[t]);
    __syncthreads();
    int idx = b * 256 + t;                         // 147456 total
    int n = idx / 768, c = idx - (idx / 768) * 768;
    int k = c >> 8, col = c & 255;
    int isI = col >> 7, j = col & 127;
    const float* ap = (isI ? i1 : r1) + (size_t)k * DIN * EMB + j;
    const float* bp = (isI ? r1 : i1) + (size_t)k * DIN * EMB + j;
    float sgn = isI ? -1.f : 1.f;
    float acc = 0.f;
    int m = 0;
    for (int f = 0; f < DIN; ++f) {
      acc = fmaf(cs[m], ap[(size_t)f * EMB], fmaf(sgn * sn[m], bp[(size_t)f * EMB], acc));
      m += n; if (m >= 192) m -= 192;
    }
    int kc = n >> 5, quad = (n & 31) >> 3, jj = n & 7;
    int lane = quad * 16 + (col & 15);
    Wb[((((k * 6 + kc) * 16 + (col >> 4)) * 64) + lane) * 8 + jj] = __float2bfloat16(acc);
  } else if (b < 640) {
    // M[j][j2] = sum_t comb_w[2j][t] * lin_w[t][j2]
    int idx = (b - 576) * 256 + t;                 // 16384
    int j = idx >> 7, j2 = idx & 127;
    float acc = 0.f;
    for (int tt = 0; tt < 128; ++tt)
      acc = fmaf(comb_w[(2 * j) * 128 + tt], lin_w[tt * 128 + j2], acc);
    M[idx] = acc;
  } else if (b < 1024) {
    // Phi
    for (int i = t; i < 384; i += 256)
      sincosf((2.f * PI_F / 384.f) * (float)i, &sn[i], &cs[i]);
    __syncthreads();
    int idx = (b - 640) * 256 + t;                 // 98304
    int slot = idx >> 7, j1 = idx & 127;
    int k = slot >> 8, r = slot & 255;
    int isI = r >> 7;
    int f = k * 128 + (r & 127);
    const float* tp = isI ? sn : cs;
    float sg = isI ? -1.f : 1.f;
    float acc = 0.f;
    int m = 0;
    for (int n = 0; n < 384; ++n) {
      acc = fmaf(sg * tp[m], fre_w[n * 128 + j1], acc);
      m += f; if (m >= 384) m -= 384;
    }
    Phi[slot * 128 + j1] = acc * (1.f / 384.f);
  } else {
    // per-node ||hidden[n]||^2
    const int w = t >> 6, lane = t & 63;
    const int n = (b - 1024) * 4 + w;              // 12500*4 = 50000
    const float2 v = ((const float2*)(hidden + (size_t)n * 128))[lane];
    float ss = v.x * v.x + v.y * v.y;
#pragma unroll
    for (int off = 32; off > 0; off >>= 1) ss += __shfl_xor(ss, off, 64);
    if (lane == 0) norms[n] = ss;
  }
}

// ---- P2: g2(384) | energy+hist(1250) ----
__global__ __launch_bounds__(256) void k_prep2(
    const float* __restrict__ Phi, const float* __restrict__ M,
    float* __restrict__ G2, __hip_bfloat16* __restrict__ G2b,
    const float* __restrict__ norms, const float* __restrict__ eattr,
    const float* __restrict__ ett, const int* __restrict__ eidx,
    float* __restrict__ energies, float* __restrict__ esum,
    int* __restrict__ cnt) {
  const int t = threadIdx.x;
  const int b = blockIdx.x;
  if (b < 384) {
    int idx = b * 256 + t;                         // 98304
    int slot = idx >> 7, j2 = idx & 127;
    float acc = 0.f;
    for (int j1 = 0; j1 < 128; ++j1)
      acc = fmaf(Phi[slot * 128 + j1], M[j1 * 128 + j2], acc);
    G2[idx] = acc;
    int k = slot >> 8, s = slot & 255;
    int kc = s >> 5, quad = (s & 31) >> 3, jj = s & 7;
    G2b[((((k * 8 + kc) * 8 + (j2 >> 4)) * 64) + quad * 16 + (j2 & 15)) * 8 + jj] =
        __float2bfloat16(acc);
  } else {
    int e = (b - 384) * 256 + t;
    float ss = norms[eidx[e]];
    const float4* a4 = (const float4*)(eattr + (size_t)e * 32);
#pragma unroll
    for (int i = 0; i < 8; ++i) {
      float4 v = a4[i];
      ss += v.x * v.x + v.y * v.y + v.z * v.z + v.w * v.w;
    }
    const float4* t4 = (const float4*)(ett + (size_t)e * 32);
#pragma unroll
    for (int i = 0; i < 8; ++i) {
      float4 v = t4[i];
      ss += v.x * v.x + v.y * v.y + v.z * v.z + v.w * v.w;
    }
    float en = 192.f * ss;
    energies[e] = en;
    float tot = en;
#pragma unroll
    for (int off = 32; off > 0; off >>= 1) tot += __shfl_down(tot, off, 64);
    if ((t & 63) == 0) atomicAdd(esum, tot);
    atomicAdd(&cnt[eidx[NEDGES + e]], 1);          // histogram
  }
}

// ---- P3: small(5) | scanA(196) ----
__global__ __launch_bounds__(256) void k_prep3(
    const float* __restrict__ rb1, const float* __restrict__ ib1,
    const float* __restrict__ fre_b, const float* __restrict__ comb_b,
    const float* __restrict__ lin_w, const float* __restrict__ M,
    const float* __restrict__ G2, float* __restrict__ bb,
    float* __restrict__ gb2, float* __restrict__ ck,
    int* __restrict__ cnt, int* __restrict__ part) {
  __shared__ int sm[256];
  const int t = threadIdx.x;
  const int b = blockIdx.x;
  if (b < 5) {
    int idx = b * 256 + t;                         // 1280
    if (idx < 768) {
      int k = idx >> 8, r = idx & 255;
      bb[idx] = (r >= 128) ? ib1[k * 128 + (r & 127)] : rb1[k * 128 + r];
    } else if (idx < 896) {
      int j2 = idx - 768;
      float acc = 0.f;
      for (int j = 0; j < 128; ++j) acc += fre_b[j] * M[j * 128 + j2];
      for (int tt = 0; tt < 128; ++tt) acc += comb_b[tt] * lin_w[tt * 128 + j2];
      gb2[j2] = acc;
    } else if (idx < 1280) {
      int q = idx - 896;
      int k = q >> 7, j2 = q & 127;
      float acc = 0.f;
      for (int j = 0; j < 128; ++j) {
        float vr = rb1[k * 128 + j];
        vr = fmaxf(vr, 0.f); vr = (vr > LAM) ? vr - LAM : 0.f;
        float vi = ib1[k * 128 + j];
        vi = fmaxf(vi, 0.f); vi = (vi > LAM) ? vi - LAM : 0.f;
        acc += vr * G2[(k * 256 + j) * 128 + j2] + vi * G2[(k * 256 + 128 + j) * 128 + j2];
      }
      ck[k * 128 + j2] = acc;
    }
  } else {
    int blk = b - 5;
    int i = blk * 256 + t;
    int v = (i < NNODES) ? cnt[i] : 0;
    sm[t] = v;
    __syncthreads();
#pragma unroll
    for (int off = 1; off < 256; off <<= 1) {
      int x = (t >= off) ? sm[t - off] : 0;
      __syncthreads();
      sm[t] += x;
      __syncthreads();
    }
    cnt[i] = sm[t] - v;                            // exclusive, in place
    if (t == 255) part[blk] = sm[t];
  }
}

__global__ __launch_bounds__(256) void k_scanB(int* __restrict__ part) {
  __shared__ int sm[256];
  const int t = threadIdx.x;
  int v = (t < SCAN_B) ? part[t] : 0;
  sm[t] = v;
  __syncthreads();
#pragma unroll
  for (int off = 1; off < 256; off <<= 1) {
    int x = (t >= off) ? sm[t - off] : 0;
    __syncthreads();
    sm[t] += x;
    __syncthreads();
  }
  if (t < SCAN_B) part[t] = sm[t] - v;
}

__global__ __launch_bounds__(256) void k_scanC(const int* __restrict__ scanned,
                                               const int* __restrict__ part,
                                               int* __restrict__ cur) {
  int i = blockIdx.x * 256 + threadIdx.x;
  cur[i] = scanned[i] + part[blockIdx.x];
}

__global__ __launch_bounds__(256) void k_fill(const int* __restrict__ eidx,
                                              int* __restrict__ cur,
                                              int* __restrict__ eids) {
  int e = blockIdx.x * 256 + threadIdx.x;
  int pos = atomicAdd(&cur[eidx[NEDGES + e]], 1);
  eids[pos] = e;
}

// ---- main edge kernel: 64 dst-sorted edges/block, 512 threads (8 waves) ----
// stage A: X[64x192] @ Wband[192x256]; wave w -> col-tiles {2w,2w+1}, rows 0..63
// stage B: O'[64x256] @ G2band[256x128]; wave w -> col-tile w
#define XS_STR 200
#define OS_STR 264
#define ZS_STR 130
__global__ __launch_bounds__(512, 4) void k_edges(
    const float* __restrict__ hidden, const float* __restrict__ eattr,
    const float* __restrict__ ett, const float* __restrict__ alpha,
    const int* __restrict__ eidx, const int* __restrict__ eids,
    const __hip_bfloat16* __restrict__ Wb, const __hip_bfloat16* __restrict__ G2b,
    const float* __restrict__ bb, const float* __restrict__ gb2,
    const float* __restrict__ ck, const float* __restrict__ energies,
    const float* __restrict__ esum, float* __restrict__ accum) {
  // Xs (25600 B) + Os (33792 B) live through the band loop; Zs (33280 B)
  // reuses the same region after the final band.
  __shared__ __align__(16) char smem[64 * XS_STR * 2 + 64 * OS_STR * 2];
  short* Xs = (short*)smem;
  short* Os = (short*)(smem + 64 * XS_STR * 2);
  float* Zs = (float*)smem;
  __shared__ float maskf[3][64];
  __shared__ int eid_s[64], srcs[64], dsts[64];
  __shared__ int tileact[3];

  const int t = threadIdx.x;
  const int e0 = blockIdx.x * 64;
  const int lane = t & 63, w = t >> 6;
  const int quad = lane >> 4, lc = lane & 15;

  if (t < 3) tileact[t] = 0;
  if (t < 64) {
    int eid = eids[e0 + t];
    eid_s[t] = eid;
    srcs[t] = eidx[eid];
    dsts[t] = eidx[NEDGES + eid];                  // non-decreasing across t
    float en = energies[eid];
    float es = *esum;
#pragma unroll
    for (int k = 0; k < NB; ++k) {
      float a = alpha[k];
      float factor = (2.f * (k + 1) - 1.f) / (2.f * NB);
      float Q = a * factor * es;
      float b = es / (a * (2.f * NB));
      bool m = (en >= Q - b) && (en <= Q + b);
      maskf[k][t] = m ? 1.f : 0.f;
      if (m) atomicOr(&tileact[k], 1);
    }
  }
  __syncthreads();

  // gather x = [hidden[src] | edge_attr | edge_time_emb] -> bf16 LDS
#pragma unroll
  for (int it = 0; it < 4; ++it) {
    int i = t + it * 512;                           // < 2048
    int e = i >> 5, c4 = i & 31;
    const float4 v = *(const float4*)(hidden + (size_t)srcs[e] * 128 + c4 * 4);
    unsigned* p = (unsigned*)&Xs[e * XS_STR + c4 * 4];
    p[0] = pk2(v.x, v.y); p[1] = pk2(v.z, v.w);
  }
#pragma unroll
  for (int it = 0; it < 2; ++it) {
    int i = t + it * 512;                           // < 1024
    int e = i >> 4, q = i & 15;
    float4 v;
    if (q < 8) v = ((const float4*)(eattr + (size_t)eid_s[e] * 32))[q];
    else       v = ((const float4*)(ett + (size_t)eid_s[e] * 32))[q - 8];
    unsigned* p = (unsigned*)&Xs[e * XS_STR + 128 + q * 4];
    p[0] = pk2(v.x, v.y); p[1] = pk2(v.z, v.w);
  }
  __syncthreads();

  v4f acc2[4];
#pragma unroll
  for (int mt = 0; mt < 4; ++mt)
#pragma unroll
    for (int r = 0; r < 4; ++r) acc2[mt][r] = 0.f;

  for (int k = 0; k < NB; ++k) {
    if (!tileact[k]) continue;                      // block-uniform
    v4f accA[4][2];
#pragma unroll
    for (int mt = 0; mt < 4; ++mt)
#pragma unroll
      for (int n = 0; n < 2; ++n)
#pragma unroll
        for (int r = 0; r < 4; ++r) accA[mt][n][r] = 0.f;

#pragma unroll
    for (int kc = 0; kc < 6; ++kc) {
      v8s af[4];
#pragma unroll
      for (int mt = 0; mt < 4; ++mt)
        af[mt] = *(const v8s*)&Xs[(mt * 16 + lc) * XS_STR + kc * 32 + quad * 8];
      const __hip_bfloat16* wp = Wb + ((((k * 6 + kc) * 16 + 2 * w) * 64) + lane) * 8;
#pragma unroll
      for (int ntl = 0; ntl < 2; ++ntl) {
        v8s bfr = *(const v8s*)(const void*)(wp + ntl * 512);
#pragma unroll
        for (int mt = 0; mt < 4; ++mt)
          accA[mt][ntl] =
              __builtin_amdgcn_mfma_f32_16x16x32_bf16(af[mt], bfr, accA[mt][ntl], 0, 0, 0);
      }
    }
    __syncthreads();  // protect Os WAR vs previous band's stage B reads
    // nonlinearity -> Os (bf16)
#pragma unroll
    for (int mt = 0; mt < 4; ++mt)
#pragma unroll
      for (int ntl = 0; ntl < 2; ++ntl) {
        int col = w * 32 + ntl * 16 + lc;
        float bbv = bb[k * 256 + col];
#pragma unroll
        for (int reg = 0; reg < 4; ++reg) {
          int row = mt * 16 + quad * 4 + reg;
          float mk = maskf[k][row];
          float v = fmaf(mk, accA[mt][ntl][reg], bbv);
          v = fmaxf(v, 0.f);
          v = (v > LAM) ? v - LAM : 0.f;
          __hip_bfloat16 h = __float2bfloat16(v);
          Os[row * OS_STR + col] = *reinterpret_cast<short*>(&h);
        }
      }
    __syncthreads();
    // stage B: acc2 += O' @ G2_band ; wave w -> cols w*16..w*16+15
#pragma unroll
    for (int kc = 0; kc < 8; ++kc) {
      v8s of[4];
#pragma unroll
      for (int mt = 0; mt < 4; ++mt)
        of[mt] = *(const v8s*)&Os[(mt * 16 + lc) * OS_STR + kc * 32 + quad * 8];
      const __hip_bfloat16* gp = G2b + ((((k * 8 + kc) * 8 + w) * 64) + lane) * 8;
      v8s bfr = *(const v8s*)(const void*)gp;
#pragma unroll
      for (int mt = 0; mt < 4; ++mt)
        acc2[mt] = __builtin_amdgcn_mfma_f32_16x16x32_bf16(of[mt], bfr, acc2[mt], 0, 0, 0);
    }
  }

  // ---- epilogue: z -> Zs (LDS), then segmented reduce (2 waves) + atomics ----
  __syncthreads();                                  // Xs/Os dead; reuse as Zs
  {
    int col = w * 16 + lc;
    float base = gb2[col];
#pragma unroll
    for (int k = 0; k < NB; ++k)
      if (!tileact[k]) base += ck[k * 128 + col];
#pragma unroll
    for (int mt = 0; mt < 4; ++mt)
#pragma unroll
      for (int reg = 0; reg < 4; ++reg) {
        int row = mt * 16 + quad * 4 + reg;
        Zs[row * ZS_STR + col] = acc2[mt][reg] + base;
      }
  }
  __syncthreads();
  if (w < 2) {
    int c = 2 * lane;
    int r0 = w * 32;
    float s0 = 0.f, s1 = 0.f;
#pragma unroll
    for (int r = 0; r < 32; ++r) {
      int row = r0 + r;
      s0 += Zs[row * ZS_STR + c];
      s1 += Zs[row * ZS_STR + c + 1];
      int d = dsts[row];
      if (r == 31 || dsts[row + 1] != d) {
        atomic2(accum + (size_t)d * 128 + c, s0, s1);
        s0 = 0.f; s1 = 0.f;
      }
    }
  }
}

// node kernel: acc + boundary@lin_w + lin_b -> LayerNorm -> relu
__global__ __launch_bounds__(256) void k_nodes(const float* __restrict__ boundary,
                                               const float* __restrict__ lin_w,
                                               const float* __restrict__ lin_b,
                                               const float* __restrict__ ln_g,
                                               const float* __restrict__ ln_b,
                                               float* __restrict__ out) {
  __shared__ float lw[32][128];
  const int t = threadIdx.x;
  const int w = t >> 6, lane = t & 63;
  const int n = blockIdx.x * 4 + w;
  float a0 = out[(size_t)n * 128 + lane] + lin_b[lane];
  float a1 = out[(size_t)n * 128 + 64 + lane] + lin_b[64 + lane];
  for (int cb = 0; cb < 128; cb += 32) {
    __syncthreads();
#pragma unroll
    for (int it = 0; it < 16; ++it) {
      int i = t + it * 256;
      lw[i >> 7][i & 127] = lin_w[(cb + (i >> 7)) * 128 + (i & 127)];
    }
    __syncthreads();
#pragma unroll
    for (int r = 0; r < 32; ++r) {
      float bv = boundary[(size_t)n * 128 + cb + r];
      a0 = fmaf(bv, lw[r][lane], a0);
      a1 = fmaf(bv, lw[r][64 + lane], a1);
    }
  }
  float s = a0 + a1, sq = a0 * a0 + a1 * a1;
#pragma unroll
  for (int off = 32; off > 0; off >>= 1) {
    s += __shfl_xor(s, off, 64);
    sq += __shfl_xor(sq, off, 64);
  }
  float mu = s * (1.f / 128.f);
  float var = sq * (1.f / 128.f) - mu * mu;
  float rs = 1.f / sqrtf(var + LN_EPS);
  float y0 = (a0 - mu) * rs * ln_g[lane] + ln_b[lane];
  float y1 = (a1 - mu) * rs * ln_g[64 + lane] + ln_b[64 + lane];
  out[(size_t)n * 128 + lane] = fmaxf(y0, 0.f);
  out[(size_t)n * 128 + 64 + lane] = fmaxf(y1, 0.f);
}

extern "C" void kernel_launch(void* const* d_in, const int* in_sizes, int n_in,
                              void* d_out, int out_size, void* d_ws, size_t ws_size,
                              hipStream_t stream) {
  const float* hidden   = (const float*)d_in[0];
  const float* eattr    = (const float*)d_in[1];
  const float* ett      = (const float*)d_in[2];
  const float* boundary = (const float*)d_in[3];
  const float* alpha    = (const float*)d_in[4];
  const float* r1       = (const float*)d_in[5];
  const float* i1       = (const float*)d_in[6];
  const float* rb1      = (const float*)d_in[7];
  const float* ib1      = (const float*)d_in[8];
  const float* fre_w    = (const float*)d_in[9];
  const float* fre_b    = (const float*)d_in[10];
  const float* comb_w   = (const float*)d_in[11];
  const float* comb_b   = (const float*)d_in[12];
  const float* lin_w    = (const float*)d_in[13];
  const float* lin_b    = (const float*)d_in[14];
  const float* ln_g     = (const float*)d_in[15];
  const float* ln_b     = (const float*)d_in[16];
  const int*   eidx     = (const int*)d_in[17];
  float* ws  = (float*)d_ws;
  float* out = (float*)d_out;
  __hip_bfloat16* Wb  = (__hip_bfloat16*)(ws + WS_WB);
  __hip_bfloat16* G2b = (__hip_bfloat16*)(ws + WS_G2B);
  int* cnt  = (int*)(ws + WS_CNT);
  int* cur  = (int*)(ws + WS_CUR);
  int* part = (int*)(ws + WS_PART);
  int* eids = (int*)(ws + WS_EIDS);

  hipMemsetAsync(ws + WS_ESUM, 0, 16 * sizeof(float), stream);
  hipMemsetAsync(cnt, 0, SCAN_N * sizeof(int), stream);
  hipMemsetAsync(out, 0, (size_t)NNODES * EMB * sizeof(float), stream);

  k_prep1<<<1024 + 12500, 256, 0, stream>>>(r1, i1, Wb, comb_w, lin_w, ws + WS_M,
                                            fre_w, ws + WS_PHI, hidden, ws + WS_NORM);
  k_prep2<<<384 + NEDGES / 256, 256, 0, stream>>>(ws + WS_PHI, ws + WS_M, ws + WS_G2,
                                                  G2b, ws + WS_NORM, eattr, ett, eidx,
                                                  ws + WS_EN, ws + WS_ESUM, cnt);
  k_prep3<<<5 + SCAN_B, 256, 0, stream>>>(rb1, ib1, fre_b, comb_b, lin_w, ws + WS_M,
                                          ws + WS_G2, ws + WS_BB, ws + WS_GB2,
                                          ws + WS_CK, cnt, part);
  k_scanB<<<1, 256, 0, stream>>>(part);
  k_scanC<<<SCAN_B, 256, 0, stream>>>(cnt, part, cur);
  k_fill<<<NEDGES / 256, 256, 0, stream>>>(eidx, cur, eids);
  k_edges<<<NEDGES / 64, 512, 0, stream>>>(hidden, eattr, ett, alpha, eidx, eids,
                                           Wb, G2b, ws + WS_BB, ws + WS_GB2,
                                           ws + WS_CK, ws + WS_EN, ws + WS_ESUM, out);
  k_nodes<<<NNODES / 4, 256, 0, stream>>>(boundary, lin_w, lin_b, ln_g, ln_b, out);
}